// Round 7
// baseline (351.753 us; speedup 1.0000x reference)
//
#include <hip/hip_runtime.h>

#define NN 50000
#define NE 1600000
#define FIN 128
#define FOUT 64
#define ALPHA 0.2f

#define RANGE 256          // destination nodes per bucket
#define NB 196             // ceil(NN / RANGE)
#define EPB 1024           // edges per block in pass A / bucket-hist (512 thr x 2)

// ---------- int width sniffer: int32 (0) vs int64 (1) ----------
__global__ void k_sniff(const int* __restrict__ edge32, int* __restrict__ iflag) {
    __shared__ int zodd;
    if (threadIdx.x == 0) zodd = 0;
    __syncthreads();
    int z = 0;
    for (int i = threadIdx.x; i < 2048; i += 256)
        if (edge32[2 * i + 1] == 0) z++;        // int64 high words are always 0
    atomicAdd(&zodd, z);
    __syncthreads();
    if (threadIdx.x == 0) *iflag = (zodd > 2000) ? 1 : 0;
}

__device__ inline int ldi(const void* p, size_t i, int isi64) {
    int v = isi64 ? (int)((const long long*)p)[i] : ((const int*)p)[i];
    return v < 0 ? 0 : (v >= NN ? NN - 1 : v);  // clamp: no data-dependent OOB
}

// f32 -> bf16 round-to-nearest-even
__device__ inline unsigned short f2bf(float x) {
    unsigned u = __float_as_uint(x);
    return (unsigned short)((u + 0x7FFFu + ((u >> 16) & 1u)) >> 16);
}

// ---------- K0: u = W @ {a1l,a1r,a2l,a2r} ----------
__global__ void k_u(const float* __restrict__ W, const float* __restrict__ a1,
                    const float* __restrict__ a2, float* __restrict__ u) {
    int k = threadIdx.x;  // 0..127
    float u1 = 0.f, u2 = 0.f, u3 = 0.f, u4 = 0.f;
    for (int j = 0; j < FOUT; j++) {
        float w = W[k * FOUT + j];
        u1 += w * a1[j];
        u2 += w * a1[FOUT + j];
        u3 += w * a2[j];
        u4 += w * a2[FOUT + j];
    }
    u[k] = u1; u[128 + k] = u2; u[256 + k] = u3; u[384 + k] = u4;
}

// ---------- K1: h = input @ W  (N x 64, stored bf16 — consumed only by k_agg) ----------
__global__ __launch_bounds__(256) void k_gemm(const float* __restrict__ X,
                                              const float* __restrict__ W,
                                              unsigned short* __restrict__ h) {
    __shared__ float wlds[FIN * FOUT];      // 32 KB
    __shared__ float xlds[4][4][FIN];       // 8 KB
    int tid = threadIdx.x;
    for (int i = tid; i < FIN * FOUT; i += 256) wlds[i] = W[i];
    int wave = tid >> 6, lane = tid & 63;
    int base = blockIdx.x * 16 + wave * 4;  // 3125*16 = 50000 exact
    for (int n0 = 0; n0 < 4; n0++) {
        float2 b = ((const float2*)(X + (size_t)(base + n0) * FIN))[lane];
        xlds[wave][n0][2 * lane] = b.x;
        xlds[wave][n0][2 * lane + 1] = b.y;
    }
    __syncthreads();
    float a0 = 0.f, a1v = 0.f, a2v = 0.f, a3 = 0.f;
    for (int k = 0; k < FIN; k++) {
        float w = wlds[k * FOUT + lane];
        a0  += xlds[wave][0][k] * w;
        a1v += xlds[wave][1][k] * w;
        a2v += xlds[wave][2][k] * w;
        a3  += xlds[wave][3][k] * w;
    }
    h[(size_t)(base + 0) * FOUT + lane] = f2bf(a0);
    h[(size_t)(base + 1) * FOUT + lane] = f2bf(a1v);
    h[(size_t)(base + 2) * FOUT + lane] = f2bf(a2v);
    h[(size_t)(base + 3) * FOUT + lane] = f2bf(a3);
}

// ---------- K1b: per-node score scalars (one wave per node) ----------
// s3 goes to sc[v].x (paired with ecs -> one 8B gather in k_edgeA).
__global__ __launch_bounds__(256) void k_svec(const float* __restrict__ input,
                                              const float* __restrict__ p_h,
                                              const float* __restrict__ new_h,
                                              const float* __restrict__ u,
                                              float* __restrict__ s1, float* __restrict__ s2,
                                              float* __restrict__ sc /* float2 as float* */,
                                              float* __restrict__ s4) {
    int lane = threadIdx.x & 63;
    int v = blockIdx.x * 4 + (threadIdx.x >> 6);
    size_t row = (size_t)v * FIN;
    float2 bi = ((const float2*)(input + row))[lane];
    float2 bp = ((const float2*)(p_h   + row))[lane];
    float2 bn = ((const float2*)(new_h + row))[lane];
    float p1 = bi.x * u[2 * lane]       + bi.y * u[2 * lane + 1];
    float p2 = bp.x * u[128 + 2 * lane] + bp.y * u[128 + 2 * lane + 1];
    float p3 = bn.x * u[256 + 2 * lane] + bn.y * u[256 + 2 * lane + 1];
    float p4 = bi.x * u[384 + 2 * lane] + bi.y * u[384 + 2 * lane + 1];
#pragma unroll
    for (int off = 32; off > 0; off >>= 1) {
        p1 += __shfl_down(p1, off, 64);
        p2 += __shfl_down(p2, off, 64);
        p3 += __shfl_down(p3, off, 64);
        p4 += __shfl_down(p4, off, 64);
    }
    if (lane == 0) { s1[v] = p1; s2[v] = p2; sc[2 * v] = p3; s4[v] = p4; }
}

// ---------- K2: col score + exp + segment max ----------
__global__ void k_colscore(const float* __restrict__ s1, const float* __restrict__ s2,
                           const void* __restrict__ edge_col, const void* __restrict__ row_i,
                           const int* __restrict__ iflag,
                           float* __restrict__ ec, unsigned int* __restrict__ m) {
    int i = blockIdx.x * 256 + threadIdx.x;
    if (i >= NN) return;
    int i64 = *iflag;
    float cs = s1[ldi(edge_col, i, i64)] + s2[i];
    float l = cs > 0.f ? cs : ALPHA * cs;
    float e = expf(-l);                // > 0 always
    ec[i] = e;
    atomicMax(&m[ldi(row_i, i, i64)], __float_as_uint(e));  // init 0, e>0 -> valid
}

// ---------- K3: ex = exp(ec - m) in place; segment sum ----------
__global__ void k_expsum(float* __restrict__ ec, const unsigned int* __restrict__ m,
                         const void* __restrict__ row_i, const int* __restrict__ iflag,
                         float* __restrict__ ssum) {
    int i = blockIdx.x * 256 + threadIdx.x;
    if (i >= NN) return;
    int r = ldi(row_i, i, *iflag);
    float e = expf(ec[i] - __uint_as_float(m[r]));
    ec[i] = e;
    atomicAdd(&ssum[r], e);
}

// ---------- K4: normalize -> sc[i].y = ecs ----------
__global__ void k_norm(const float* __restrict__ ex, const float* __restrict__ ssum,
                       const void* __restrict__ row_i, const int* __restrict__ iflag,
                       float* __restrict__ sc /* float2 as float* */) {
    int i = blockIdx.x * 256 + threadIdx.x;
    if (i >= NN) return;
    sc[2 * i + 1] = ex[i] / (ssum[ldi(row_i, i, *iflag)] + 1e-16f);
}

// ---------- K5a: bucket histogram (196 bins, LDS-privatized, 512 thr x 2) ----------
__global__ __launch_bounds__(512) void k_bhist(const void* __restrict__ edge,
                                               const int* __restrict__ iflag,
                                               int* __restrict__ bcnt) {
    __shared__ int hist[NB];
    int tid = threadIdx.x;
    for (int t = tid; t < NB; t += 512) hist[t] = 0;
    __syncthreads();
    int i64 = *iflag;
    int base = blockIdx.x * EPB;
#pragma unroll
    for (int k = 0; k < 2; k++) {
        int e = base + k * 512 + tid;
        if (e < NE) atomicAdd(&hist[ldi(edge, e, i64) >> 8], 1);
    }
    __syncthreads();
    for (int t = tid; t < NB; t += 512)
        if (hist[t]) atomicAdd(&bcnt[t], hist[t]);
}

// ---------- K5b: scan 196 bucket counts -> bstart, bcur; sentinels ----------
__global__ __launch_bounds__(256) void k_bscan(const int* __restrict__ bcnt,
                                               int* __restrict__ bstart, int* __restrict__ bcur,
                                               int* __restrict__ start) {
    __shared__ int s[256];
    int tid = threadIdx.x;
    int x = (tid < NB) ? bcnt[tid] : 0;
    s[tid] = x;
    __syncthreads();
    for (int off = 1; off < 256; off <<= 1) {
        int t = (tid >= off) ? s[tid - off] : 0;
        __syncthreads();
        s[tid] += t;
        __syncthreads();
    }
    if (tid < NB) { int e = s[tid] - x; bstart[tid] = e; bcur[tid] = e; }
    if (tid == 0) { bstart[NB] = NE; start[NN] = NE; }
}

// ---------- K5c pass A: per-edge score + LDS-binned coarse scatter ----------
// EPB=1024 (1563 blocks ~ 6.1 blocks/CU): 2x resident waves vs EPB=2048 to
// hide the random-gather latency (was 39% occupancy, nothing else busy).
// sc[rr] is one 8B gather ({s3, ecs}) instead of two 4B gathers.
__global__ __launch_bounds__(512) void k_edgeA(const float2* __restrict__ sc, const float* __restrict__ s4,
                                               const void* __restrict__ edge, const void* __restrict__ row_resort,
                                               const int* __restrict__ iflag,
                                               int* __restrict__ bcur, uint2* __restrict__ tmp,
                                               float* __restrict__ edge_e /* = out2 */) {
    __shared__ int hist[NB];
    __shared__ int bbase[NB];
    int tid = threadIdx.x;
    for (int t = tid; t < NB; t += 512) hist[t] = 0;
    __syncthreads();
    int i64 = *iflag;
    int base = blockIdx.x * EPB;
    unsigned int key[2]; float val[2]; int rk[2], bk[2];
#pragma unroll
    for (int k = 0; k < 2; k++) {
        int e = base + k * 512 + tid;
        bk[k] = -1;
        if (e < NE) {
            int e0 = ldi(edge, e, i64);
            int e1 = ldi(edge, (size_t)NE + e, i64);
            int rr = ldi(row_resort, e, i64);
            float2 c = sc[rr];                         // {s3, ecs} one gather
            float rs = c.x + s4[e1];
            float l = rs > 0.f ? rs : ALPHA * rs;
            float ee = expf(-l) * c.y;
            edge_e[e] = ee;                           // numerator for out2 (sequential)
            key[k] = (unsigned int)e0 | ((unsigned int)e1 << 16);  // both < 65536
            val[k] = ee;
            bk[k] = e0 >> 8;                          // bucket = e0 / RANGE
            rk[k] = atomicAdd(&hist[bk[k]], 1);       // rank within (block, bucket)
        }
    }
    __syncthreads();
    for (int t = tid; t < NB; t += 512)
        bbase[t] = atomicAdd(&bcur[t], hist[t]);      // reserve contiguous run
    __syncthreads();
#pragma unroll
    for (int k = 0; k < 2; k++)
        if (bk[k] >= 0)
            tmp[bbase[bk[k]] + rk[k]] = make_uint2(key[k], __float_as_uint(val[k]));
}

// ---------- K5c pass B: per-node offsets + fine scatter, L2-resident ----------
__global__ __launch_bounds__(512) void k_edgeB(const uint2* __restrict__ tmp,
                                               const int* __restrict__ bstart,
                                               int* __restrict__ start,
                                               float2* __restrict__ pairs) {
    __shared__ int cnt[RANGE];
    __shared__ int s[RANGE];
    __shared__ int cur[RANGE];
    int b = blockIdx.x;
    int tid = threadIdx.x;
    int v0 = b * RANGE;
    if (tid < RANGE) cnt[tid] = 0;
    __syncthreads();
    int lo = bstart[b], hi = bstart[b + 1];
    for (int i = lo + tid; i < hi; i += 512)
        atomicAdd(&cnt[tmp[i].x & 0xFFu], 1);         // e0 & 255 == e0 - v0
    __syncthreads();
    if (tid < RANGE) s[tid] = cnt[tid];
    __syncthreads();
    for (int off = 1; off < RANGE; off <<= 1) {
        int t = 0;
        if (tid < RANGE && tid >= off) t = s[tid - off];
        __syncthreads();
        if (tid < RANGE) s[tid] += t;
        __syncthreads();
    }
    if (tid < RANGE) {
        int g = lo + s[tid] - cnt[tid];               // exclusive prefix + bucket base
        cur[tid] = g;
        int v = v0 + tid;
        if (v < NN) start[v] = g;
    }
    __syncthreads();
    for (int i = lo + tid; i < hi; i += 512) {
        uint2 r = tmp[i];
        int pos = atomicAdd(&cur[r.x & 0xFFu], 1);    // LDS atomic
        pairs[pos] = make_float2(__int_as_float((int)(r.x >> 16)), __uint_as_float(r.y));
    }
}

// ---------- K6: gather-aggregate per node; 4 edges per wave-instruction ----------
__global__ __launch_bounds__(512) void k_agg(const unsigned short* __restrict__ h,
                                             const float2* __restrict__ pairs,
                                             const int* __restrict__ start,
                                             float* __restrict__ ersum,
                                             float* __restrict__ out0) {
    int lane = threadIdx.x & 63;
    int q  = lane >> 4;                // edge slot within group of 4
    int fq = lane & 15;                // feature quad: feats 4fq..4fq+3
    int v = blockIdx.x * 8 + (threadIdx.x >> 6);      // 6250*8 = NN exact
    int a = start[v], b = start[v + 1];
    float acc0 = 0.f, acc1 = 0.f, acc2 = 0.f, acc3 = 0.f, rs = 0.f;
    for (int j = a; j < b; j += 8) {
        int eA = j + q, eB = j + 4 + q;
        float2 pA = (eA < b) ? pairs[eA] : make_float2(__int_as_float(0), 0.f);
        float2 pB = (eB < b) ? pairs[eB] : make_float2(__int_as_float(0), 0.f);
        uint2 hA = *(const uint2*)(h + (((size_t)__float_as_int(pA.x)) << 6) + 4 * fq);
        uint2 hB = *(const uint2*)(h + (((size_t)__float_as_int(pB.x)) << 6) + 4 * fq);
        acc0 += pA.y * __uint_as_float(hA.x << 16);
        acc1 += pA.y * __uint_as_float(hA.x & 0xFFFF0000u);
        acc2 += pA.y * __uint_as_float(hA.y << 16);
        acc3 += pA.y * __uint_as_float(hA.y & 0xFFFF0000u);
        acc0 += pB.y * __uint_as_float(hB.x << 16);
        acc1 += pB.y * __uint_as_float(hB.x & 0xFFFF0000u);
        acc2 += pB.y * __uint_as_float(hB.y << 16);
        acc3 += pB.y * __uint_as_float(hB.y & 0xFFFF0000u);
        rs += pA.y + pB.y;
    }
#pragma unroll
    for (int off = 16; off <= 32; off <<= 1) {
        acc0 += __shfl_xor(acc0, off, 64);
        acc1 += __shfl_xor(acc1, off, 64);
        acc2 += __shfl_xor(acc2, off, 64);
        acc3 += __shfl_xor(acc3, off, 64);
        rs   += __shfl_xor(rs, off, 64);
    }
    if (q == 0) {
        rs += (rs == 0.f) ? 1.f : 0.f;                // empty-segment fixup (ee>0 otherwise)
        float4 o;
        o.x = acc0 / rs; o.y = acc1 / rs; o.z = acc2 / rs; o.w = acc3 / rs;
        o.x = o.x > 0.f ? o.x : expm1f(o.x);
        o.y = o.y > 0.f ? o.y : expm1f(o.y);
        o.z = o.z > 0.f ? o.z : expm1f(o.z);
        o.w = o.w > 0.f ? o.w : expm1f(o.w);
        ((float4*)(out0 + (size_t)v * FOUT))[fq] = o;
        if (fq == 0) ersum[v] = rs;                   // fixed rowsum, plain store
    }
}

// ---------- K7: out1 = float(edge) AND out2 /= ersum[e0] (fused, runs LAST) ----------
__global__ __launch_bounds__(256) void k_final(const void* __restrict__ edge, const int* __restrict__ iflag,
                                               const float* __restrict__ ersum,
                                               float* __restrict__ out2, float* __restrict__ out1) {
    int i = blockIdx.x * 256 + threadIdx.x;           // 12500*256 = 2*NE exact
    int i64 = *iflag;
    int v = i64 ? (int)((const long long*)edge)[i] : ((const int*)edge)[i];
    out1[i] = (float)v;
    if (i < NE) {                                     // edge[0..NE) is row 0 = e0
        int e0 = v < 0 ? 0 : (v >= NN ? NN - 1 : v);
        out2[i] = out2[i] / ersum[e0];
    }
}

extern "C" void kernel_launch(void* const* d_in, const int* in_sizes, int n_in,
                              void* d_out, int out_size, void* d_ws, size_t ws_size,
                              hipStream_t stream) {
    // Resolve inputs by element count (all distinct).
    int ix[3] = {0, 1, 2}; int nx = 0;
    int iE = 3, iCol = 4, iRowI = 5, iRes = 6, iW = 8, iA1 = 9, iA2 = 10;
    bool a1seen = false;
    for (int i = 0; i < n_in; i++) {
        int s = in_sizes[i];
        if (s == NN * FIN) { if (nx < 3) ix[nx++] = i; }
        else if (s == 2 * NE) iE = i;
        else if (s == 2 * NN) iCol = i;
        else if (s == NN) iRowI = i;
        else if (s == NE) iRes = i;
        else if (s == FIN * FOUT) iW = i;
        else if (s == 2 * FOUT) { if (!a1seen) { iA1 = i; a1seen = true; } else iA2 = i; }
    }
    const float* input = (const float*)d_in[ix[0]];
    const float* p_h   = (const float*)d_in[ix[1]];
    const float* new_h = (const float*)d_in[ix[2]];
    const void* edge       = d_in[iE];
    const void* edge_col   = d_in[iCol];
    const void* row_i      = d_in[iRowI];
    const void* row_resort = d_in[iRes];
    const float* W  = (const float*)d_in[iW];
    const float* a1 = (const float*)d_in[iA1];
    const float* a2 = (const float*)d_in[iA2];

    // Outputs are FLOAT32, concatenated.
    float* out0 = (float*)d_out;                      // N*FOUT
    float* out1 = out0 + (size_t)NN * FOUT;           // 2*NE
    float* out2 = out1 + (size_t)2 * NE;              // NE (edge_e numerator, then in-place divide)

    // Coarse-scatter scratch: out1 region is free until k_final (last kernel).
    uint2* tmp = (uint2*)out1;

    // ws layout (~27.6 MB; h region reserved as NN*FOUT floats, used as bf16)
    unsigned short* h = (unsigned short*)d_ws;        // NN*FOUT bf16 (6.4 MB used)
    float2* pairs  = (float2*)((float*)d_ws + (size_t)NN * FOUT); // NE float2 (12.8 MB)
    float*  s1     = (float*)(pairs + NE);
    float*  s2     = s1 + NN;
    float*  s4     = s2 + NN;
    float*  ec     = s4 + NN;                         // reused in place as ex
    float*  scf    = ec + NN;                         // float2[NN]: {s3, ecs}
    float*  mseg   = scf + 2 * (size_t)NN;            // zeroed (atomicMax uint bits)
    float*  ssum   = mseg + NN;                       // zeroed
    int*    bcnt   = (int*)(ssum + NN);               // NB, zeroed (contiguous with above)
    int*    start  = bcnt + NB;                       // NN+1 (sentinel)
    int*    bstart = start + NN + 1;                  // NB+1
    int*    bcur   = bstart + NB + 1;                 // NB
    float*  ersum  = (float*)(bcur + NB);             // NN (plain stores, no zero needed)
    float*  u      = ersum + NN;                      // 512
    int*    iflag  = (int*)(u + 512);

    hipMemsetAsync(mseg, 0, ((size_t)2 * NN + NB) * sizeof(float), stream);  // mseg, ssum, bcnt

    k_sniff<<<1, 256, 0, stream>>>((const int*)edge, iflag);
    k_u<<<1, 128, 0, stream>>>(W, a1, a2, u);
    k_gemm<<<NN / 16, 256, 0, stream>>>(input, W, h);
    k_svec<<<NN / 4, 256, 0, stream>>>(input, p_h, new_h, u, s1, s2, scf, s4);
    k_colscore<<<(NN + 255) / 256, 256, 0, stream>>>(s1, s2, edge_col, row_i, iflag, ec, (unsigned int*)mseg);
    k_expsum<<<(NN + 255) / 256, 256, 0, stream>>>(ec, (const unsigned int*)mseg, row_i, iflag, ssum);
    k_norm<<<(NN + 255) / 256, 256, 0, stream>>>(ec, ssum, row_i, iflag, scf);
    k_bhist<<<(NE + EPB - 1) / EPB, 512, 0, stream>>>(edge, iflag, bcnt);
    k_bscan<<<1, 256, 0, stream>>>(bcnt, bstart, bcur, start);
    k_edgeA<<<(NE + EPB - 1) / EPB, 512, 0, stream>>>((const float2*)scf, s4, edge, row_resort, iflag, bcur, tmp, out2);
    k_edgeB<<<NB, 512, 0, stream>>>(tmp, bstart, start, pairs);
    k_agg<<<NN / 8, 512, 0, stream>>>(h, pairs, start, ersum, out0);
    k_final<<<2 * NE / 256, 256, 0, stream>>>(edge, iflag, ersum, out2, out1);
}

// Round 8
// 310.741 us; speedup vs baseline: 1.1320x; 1.1320x over previous
//
#include <hip/hip_runtime.h>

#define NN 50000
#define NE 1600000
#define FIN 128
#define FOUT 64
#define ALPHA 0.2f

#define RANGE 256          // destination nodes per bucket
#define NB 196             // ceil(NN / RANGE)
#define EPB 2048           // edges per block in pass A (512 thr x 4)
#define NBLK 782           // ceil(NE / EPB)

// ---------- int width sniffer: int32 (0) vs int64 (1) ----------
__global__ void k_sniff(const int* __restrict__ edge32, int* __restrict__ iflag) {
    __shared__ int zodd;
    if (threadIdx.x == 0) zodd = 0;
    __syncthreads();
    int z = 0;
    for (int i = threadIdx.x; i < 2048; i += 256)
        if (edge32[2 * i + 1] == 0) z++;        // int64 high words are always 0
    atomicAdd(&zodd, z);
    __syncthreads();
    if (threadIdx.x == 0) *iflag = (zodd > 2000) ? 1 : 0;
}

__device__ inline int ldi(const void* p, size_t i, int isi64) {
    int v = isi64 ? (int)((const long long*)p)[i] : ((const int*)p)[i];
    return v < 0 ? 0 : (v >= NN ? NN - 1 : v);  // clamp: no data-dependent OOB
}

// f32 -> bf16 round-to-nearest-even
__device__ inline unsigned short f2bf(float x) {
    unsigned u = __float_as_uint(x);
    return (unsigned short)((u + 0x7FFFu + ((u >> 16) & 1u)) >> 16);
}

// ---------- K0: u = W @ {a1l,a1r,a2l,a2r} ----------
__global__ void k_u(const float* __restrict__ W, const float* __restrict__ a1,
                    const float* __restrict__ a2, float* __restrict__ u) {
    int k = threadIdx.x;  // 0..127
    float u1 = 0.f, u2 = 0.f, u3 = 0.f, u4 = 0.f;
    for (int j = 0; j < FOUT; j++) {
        float w = W[k * FOUT + j];
        u1 += w * a1[j];
        u2 += w * a1[FOUT + j];
        u3 += w * a2[j];
        u4 += w * a2[FOUT + j];
    }
    u[k] = u1; u[128 + k] = u2; u[256 + k] = u3; u[384 + k] = u4;
}

// ---------- K1: h = input @ W  (N x 64, stored bf16 — consumed only by k_agg) ----------
__global__ __launch_bounds__(256) void k_gemm(const float* __restrict__ X,
                                              const float* __restrict__ W,
                                              unsigned short* __restrict__ h) {
    __shared__ float wlds[FIN * FOUT];      // 32 KB
    __shared__ float xlds[4][4][FIN];       // 8 KB
    int tid = threadIdx.x;
    for (int i = tid; i < FIN * FOUT; i += 256) wlds[i] = W[i];
    int wave = tid >> 6, lane = tid & 63;
    int base = blockIdx.x * 16 + wave * 4;  // 3125*16 = 50000 exact
    for (int n0 = 0; n0 < 4; n0++) {
        float2 b = ((const float2*)(X + (size_t)(base + n0) * FIN))[lane];
        xlds[wave][n0][2 * lane] = b.x;
        xlds[wave][n0][2 * lane + 1] = b.y;
    }
    __syncthreads();
    float a0 = 0.f, a1v = 0.f, a2v = 0.f, a3 = 0.f;
    for (int k = 0; k < FIN; k++) {
        float w = wlds[k * FOUT + lane];
        a0  += xlds[wave][0][k] * w;
        a1v += xlds[wave][1][k] * w;
        a2v += xlds[wave][2][k] * w;
        a3  += xlds[wave][3][k] * w;
    }
    h[(size_t)(base + 0) * FOUT + lane] = f2bf(a0);
    h[(size_t)(base + 1) * FOUT + lane] = f2bf(a1v);
    h[(size_t)(base + 2) * FOUT + lane] = f2bf(a2v);
    h[(size_t)(base + 3) * FOUT + lane] = f2bf(a3);
}

// ---------- K1b: per-node score scalars (one wave per node) ----------
// s3 goes to sc[v].x (paired with ecs -> one 8B gather in k_edgeA).
__global__ __launch_bounds__(256) void k_svec(const float* __restrict__ input,
                                              const float* __restrict__ p_h,
                                              const float* __restrict__ new_h,
                                              const float* __restrict__ u,
                                              float* __restrict__ s1, float* __restrict__ s2,
                                              float* __restrict__ sc /* float2 as float* */,
                                              float* __restrict__ s4) {
    int lane = threadIdx.x & 63;
    int v = blockIdx.x * 4 + (threadIdx.x >> 6);
    size_t row = (size_t)v * FIN;
    float2 bi = ((const float2*)(input + row))[lane];
    float2 bp = ((const float2*)(p_h   + row))[lane];
    float2 bn = ((const float2*)(new_h + row))[lane];
    float p1 = bi.x * u[2 * lane]       + bi.y * u[2 * lane + 1];
    float p2 = bp.x * u[128 + 2 * lane] + bp.y * u[128 + 2 * lane + 1];
    float p3 = bn.x * u[256 + 2 * lane] + bn.y * u[256 + 2 * lane + 1];
    float p4 = bi.x * u[384 + 2 * lane] + bi.y * u[384 + 2 * lane + 1];
#pragma unroll
    for (int off = 32; off > 0; off >>= 1) {
        p1 += __shfl_down(p1, off, 64);
        p2 += __shfl_down(p2, off, 64);
        p3 += __shfl_down(p3, off, 64);
        p4 += __shfl_down(p4, off, 64);
    }
    if (lane == 0) { s1[v] = p1; s2[v] = p2; sc[2 * v] = p3; s4[v] = p4; }
}

// ---------- K2: col score + exp + segment max ----------
__global__ void k_colscore(const float* __restrict__ s1, const float* __restrict__ s2,
                           const void* __restrict__ edge_col, const void* __restrict__ row_i,
                           const int* __restrict__ iflag,
                           float* __restrict__ ec, unsigned int* __restrict__ m) {
    int i = blockIdx.x * 256 + threadIdx.x;
    if (i >= NN) return;
    int i64 = *iflag;
    float cs = s1[ldi(edge_col, i, i64)] + s2[i];
    float l = cs > 0.f ? cs : ALPHA * cs;
    float e = expf(-l);                // > 0 always
    ec[i] = e;
    atomicMax(&m[ldi(row_i, i, i64)], __float_as_uint(e));  // init 0, e>0 -> valid
}

// ---------- K3: ex = exp(ec - m) in place; segment sum ----------
__global__ void k_expsum(float* __restrict__ ec, const unsigned int* __restrict__ m,
                         const void* __restrict__ row_i, const int* __restrict__ iflag,
                         float* __restrict__ ssum) {
    int i = blockIdx.x * 256 + threadIdx.x;
    if (i >= NN) return;
    int r = ldi(row_i, i, *iflag);
    float e = expf(ec[i] - __uint_as_float(m[r]));
    ec[i] = e;
    atomicAdd(&ssum[r], e);
}

// ---------- K4: normalize -> sc[i].y = ecs ----------
__global__ void k_norm(const float* __restrict__ ex, const float* __restrict__ ssum,
                       const void* __restrict__ row_i, const int* __restrict__ iflag,
                       float* __restrict__ sc /* float2 as float* */) {
    int i = blockIdx.x * 256 + threadIdx.x;
    if (i >= NN) return;
    sc[2 * i + 1] = ex[i] / (ssum[ldi(row_i, i, *iflag)] + 1e-16f);
}

// ---------- K5a: per-block bucket counts -> cntm[block][196] (NO global atomics) ----------
__global__ __launch_bounds__(512) void k_cnt(const void* __restrict__ edge,
                                             const int* __restrict__ iflag,
                                             int* __restrict__ cntm) {
    __shared__ int hist[NB];
    int tid = threadIdx.x;
    for (int t = tid; t < NB; t += 512) hist[t] = 0;
    __syncthreads();
    int i64 = *iflag;
    int base = blockIdx.x * EPB;
#pragma unroll
    for (int k = 0; k < 4; k++) {
        int e = base + k * 512 + tid;
        if (e < NE) atomicAdd(&hist[ldi(edge, e, i64) >> 8], 1);
    }
    __syncthreads();
    for (int t = tid; t < NB; t += 512)
        cntm[blockIdx.x * NB + t] = hist[t];          // plain coalesced row store
}

// ---------- K5b1: per-bucket column scan over 782 blocks -> colpre, bcnt ----------
// One block per bucket; Hillis-Steele scan of the 782-entry column in LDS.
__global__ __launch_bounds__(1024) void k_colscan(const int* __restrict__ cntm,
                                                  int* __restrict__ colpre,
                                                  int* __restrict__ bcnt) {
    __shared__ int s[1024];
    int b = blockIdx.x, tid = threadIdx.x;
    int x = (tid < NBLK) ? cntm[(size_t)tid * NB + b] : 0;
    s[tid] = x;
    __syncthreads();
    for (int off = 1; off < 1024; off <<= 1) {
        int t = (tid >= off) ? s[tid - off] : 0;
        __syncthreads();
        s[tid] += t;
        __syncthreads();
    }
    if (tid < NBLK) colpre[(size_t)tid * NB + b] = s[tid] - x;  // exclusive within column
    if (tid == 1023) bcnt[b] = s[1023];                         // column total
}

// ---------- K5b2: scan 196 bucket totals -> bstart; sentinels ----------
__global__ __launch_bounds__(256) void k_bscan(const int* __restrict__ bcnt,
                                               int* __restrict__ bstart,
                                               int* __restrict__ start) {
    __shared__ int s[256];
    int tid = threadIdx.x;
    int x = (tid < NB) ? bcnt[tid] : 0;
    s[tid] = x;
    __syncthreads();
    for (int off = 1; off < 256; off <<= 1) {
        int t = (tid >= off) ? s[tid - off] : 0;
        __syncthreads();
        s[tid] += t;
        __syncthreads();
    }
    if (tid < NB) bstart[tid] = s[tid] - x;
    if (tid == 0) { bstart[NB] = NE; start[NN] = NE; }
}

// ---------- K5c pass A: per-edge score + coarse scatter, deterministic offsets ----------
// bbase = bstart[t] + colpre[block][t] is a plain coalesced load: no global
// atomics, no wait-for-atomic-return phase (rounds 3-7 floor suspect).
__global__ __launch_bounds__(512) void k_edgeA(const float2* __restrict__ sc, const float* __restrict__ s4,
                                               const void* __restrict__ edge, const void* __restrict__ row_resort,
                                               const int* __restrict__ iflag,
                                               const int* __restrict__ bstart, const int* __restrict__ colpre,
                                               uint2* __restrict__ tmp,
                                               float* __restrict__ edge_e /* = out2 */) {
    __shared__ int hist[NB];
    __shared__ int bbase[NB];
    int tid = threadIdx.x;
    for (int t = tid; t < NB; t += 512) hist[t] = 0;
    __syncthreads();
    int i64 = *iflag;
    int base = blockIdx.x * EPB;
    unsigned int key[4]; float val[4]; int rk[4], bk[4];
#pragma unroll
    for (int k = 0; k < 4; k++) {
        int e = base + k * 512 + tid;
        bk[k] = -1;
        if (e < NE) {
            int e0 = ldi(edge, e, i64);
            int e1 = ldi(edge, (size_t)NE + e, i64);
            int rr = ldi(row_resort, e, i64);
            float2 c = sc[rr];                         // {s3, ecs} one gather
            float rs = c.x + s4[e1];
            float l = rs > 0.f ? rs : ALPHA * rs;
            float ee = expf(-l) * c.y;
            edge_e[e] = ee;                           // numerator for out2 (sequential)
            key[k] = (unsigned int)e0 | ((unsigned int)e1 << 16);  // both < 65536
            val[k] = ee;
            bk[k] = e0 >> 8;                          // bucket = e0 / RANGE
            rk[k] = atomicAdd(&hist[bk[k]], 1);       // rank within (block, bucket)
        }
    }
    __syncthreads();
    for (int t = tid; t < NB; t += 512)
        bbase[t] = bstart[t] + colpre[(size_t)blockIdx.x * NB + t];  // plain load
    __syncthreads();
#pragma unroll
    for (int k = 0; k < 4; k++)
        if (bk[k] >= 0)
            tmp[bbase[bk[k]] + rk[k]] = make_uint2(key[k], __float_as_uint(val[k]));
}

// ---------- K5c pass B: per-node offsets + fine scatter, L2-resident ----------
__global__ __launch_bounds__(512) void k_edgeB(const uint2* __restrict__ tmp,
                                               const int* __restrict__ bstart,
                                               int* __restrict__ start,
                                               float2* __restrict__ pairs) {
    __shared__ int cnt[RANGE];
    __shared__ int s[RANGE];
    __shared__ int cur[RANGE];
    int b = blockIdx.x;
    int tid = threadIdx.x;
    int v0 = b * RANGE;
    if (tid < RANGE) cnt[tid] = 0;
    __syncthreads();
    int lo = bstart[b], hi = bstart[b + 1];
    for (int i = lo + tid; i < hi; i += 512)
        atomicAdd(&cnt[tmp[i].x & 0xFFu], 1);         // e0 & 255 == e0 - v0
    __syncthreads();
    if (tid < RANGE) s[tid] = cnt[tid];
    __syncthreads();
    for (int off = 1; off < RANGE; off <<= 1) {
        int t = 0;
        if (tid < RANGE && tid >= off) t = s[tid - off];
        __syncthreads();
        if (tid < RANGE) s[tid] += t;
        __syncthreads();
    }
    if (tid < RANGE) {
        int g = lo + s[tid] - cnt[tid];               // exclusive prefix + bucket base
        cur[tid] = g;
        int v = v0 + tid;
        if (v < NN) start[v] = g;
    }
    __syncthreads();
    for (int i = lo + tid; i < hi; i += 512) {
        uint2 r = tmp[i];
        int pos = atomicAdd(&cur[r.x & 0xFFu], 1);    // LDS atomic
        pairs[pos] = make_float2(__int_as_float((int)(r.x >> 16)), __uint_as_float(r.y));
    }
}

// ---------- K6: gather-aggregate per node; 4 edges per wave-instruction ----------
__global__ __launch_bounds__(512) void k_agg(const unsigned short* __restrict__ h,
                                             const float2* __restrict__ pairs,
                                             const int* __restrict__ start,
                                             float* __restrict__ ersum,
                                             float* __restrict__ out0) {
    int lane = threadIdx.x & 63;
    int q  = lane >> 4;                // edge slot within group of 4
    int fq = lane & 15;                // feature quad: feats 4fq..4fq+3
    int v = blockIdx.x * 8 + (threadIdx.x >> 6);      // 6250*8 = NN exact
    int a = start[v], b = start[v + 1];
    float acc0 = 0.f, acc1 = 0.f, acc2 = 0.f, acc3 = 0.f, rs = 0.f;
    for (int j = a; j < b; j += 8) {
        int eA = j + q, eB = j + 4 + q;
        float2 pA = (eA < b) ? pairs[eA] : make_float2(__int_as_float(0), 0.f);
        float2 pB = (eB < b) ? pairs[eB] : make_float2(__int_as_float(0), 0.f);
        uint2 hA = *(const uint2*)(h + (((size_t)__float_as_int(pA.x)) << 6) + 4 * fq);
        uint2 hB = *(const uint2*)(h + (((size_t)__float_as_int(pB.x)) << 6) + 4 * fq);
        acc0 += pA.y * __uint_as_float(hA.x << 16);
        acc1 += pA.y * __uint_as_float(hA.x & 0xFFFF0000u);
        acc2 += pA.y * __uint_as_float(hA.y << 16);
        acc3 += pA.y * __uint_as_float(hA.y & 0xFFFF0000u);
        acc0 += pB.y * __uint_as_float(hB.x << 16);
        acc1 += pB.y * __uint_as_float(hB.x & 0xFFFF0000u);
        acc2 += pB.y * __uint_as_float(hB.y << 16);
        acc3 += pB.y * __uint_as_float(hB.y & 0xFFFF0000u);
        rs += pA.y + pB.y;
    }
#pragma unroll
    for (int off = 16; off <= 32; off <<= 1) {
        acc0 += __shfl_xor(acc0, off, 64);
        acc1 += __shfl_xor(acc1, off, 64);
        acc2 += __shfl_xor(acc2, off, 64);
        acc3 += __shfl_xor(acc3, off, 64);
        rs   += __shfl_xor(rs, off, 64);
    }
    if (q == 0) {
        rs += (rs == 0.f) ? 1.f : 0.f;                // empty-segment fixup (ee>0 otherwise)
        float4 o;
        o.x = acc0 / rs; o.y = acc1 / rs; o.z = acc2 / rs; o.w = acc3 / rs;
        o.x = o.x > 0.f ? o.x : expm1f(o.x);
        o.y = o.y > 0.f ? o.y : expm1f(o.y);
        o.z = o.z > 0.f ? o.z : expm1f(o.z);
        o.w = o.w > 0.f ? o.w : expm1f(o.w);
        ((float4*)(out0 + (size_t)v * FOUT))[fq] = o;
        if (fq == 0) ersum[v] = rs;                   // fixed rowsum, plain store
    }
}

// ---------- K7: out1 = float(edge) AND out2 /= ersum[e0] (fused, runs LAST) ----------
__global__ __launch_bounds__(256) void k_final(const void* __restrict__ edge, const int* __restrict__ iflag,
                                               const float* __restrict__ ersum,
                                               float* __restrict__ out2, float* __restrict__ out1) {
    int i = blockIdx.x * 256 + threadIdx.x;           // 12500*256 = 2*NE exact
    int i64 = *iflag;
    int v = i64 ? (int)((const long long*)edge)[i] : ((const int*)edge)[i];
    out1[i] = (float)v;
    if (i < NE) {                                     // edge[0..NE) is row 0 = e0
        int e0 = v < 0 ? 0 : (v >= NN ? NN - 1 : v);
        out2[i] = out2[i] / ersum[e0];
    }
}

extern "C" void kernel_launch(void* const* d_in, const int* in_sizes, int n_in,
                              void* d_out, int out_size, void* d_ws, size_t ws_size,
                              hipStream_t stream) {
    // Resolve inputs by element count (all distinct).
    int ix[3] = {0, 1, 2}; int nx = 0;
    int iE = 3, iCol = 4, iRowI = 5, iRes = 6, iW = 8, iA1 = 9, iA2 = 10;
    bool a1seen = false;
    for (int i = 0; i < n_in; i++) {
        int s = in_sizes[i];
        if (s == NN * FIN) { if (nx < 3) ix[nx++] = i; }
        else if (s == 2 * NE) iE = i;
        else if (s == 2 * NN) iCol = i;
        else if (s == NN) iRowI = i;
        else if (s == NE) iRes = i;
        else if (s == FIN * FOUT) iW = i;
        else if (s == 2 * FOUT) { if (!a1seen) { iA1 = i; a1seen = true; } else iA2 = i; }
    }
    const float* input = (const float*)d_in[ix[0]];
    const float* p_h   = (const float*)d_in[ix[1]];
    const float* new_h = (const float*)d_in[ix[2]];
    const void* edge       = d_in[iE];
    const void* edge_col   = d_in[iCol];
    const void* row_i      = d_in[iRowI];
    const void* row_resort = d_in[iRes];
    const float* W  = (const float*)d_in[iW];
    const float* a1 = (const float*)d_in[iA1];
    const float* a2 = (const float*)d_in[iA2];

    // Outputs are FLOAT32, concatenated.
    float* out0 = (float*)d_out;                      // N*FOUT
    float* out1 = out0 + (size_t)NN * FOUT;           // 2*NE
    float* out2 = out1 + (size_t)2 * NE;              // NE (edge_e numerator, then in-place divide)

    // Coarse-scatter scratch: out1 region is free until k_final (last kernel).
    uint2* tmp = (uint2*)out1;

    // ws layout (~29 MB; h region reserved as NN*FOUT floats, used as bf16)
    unsigned short* h = (unsigned short*)d_ws;        // NN*FOUT bf16 (6.4 MB used)
    float2* pairs  = (float2*)((float*)d_ws + (size_t)NN * FOUT); // NE float2 (12.8 MB)
    float*  s1     = (float*)(pairs + NE);
    float*  s2     = s1 + NN;
    float*  s4     = s2 + NN;
    float*  ec     = s4 + NN;                         // reused in place as ex
    float*  scf    = ec + NN;                         // float2[NN]: {s3, ecs}
    float*  mseg   = scf + 2 * (size_t)NN;            // zeroed (atomicMax uint bits)
    float*  ssum   = mseg + NN;                       // zeroed
    int*    bcnt   = (int*)(ssum + NN);               // NB
    int*    start  = bcnt + NB;                       // NN+1 (sentinel)
    int*    bstart = start + NN + 1;                  // NB+1
    int*    cntm   = bstart + NB + 1;                 // NBLK*NB (613 KB)
    int*    colpre = cntm + (size_t)NBLK * NB;        // NBLK*NB (613 KB)
    float*  ersum  = (float*)(colpre + (size_t)NBLK * NB);  // NN
    float*  u      = ersum + NN;                      // 512
    int*    iflag  = (int*)(u + 512);

    hipMemsetAsync(mseg, 0, (size_t)2 * NN * sizeof(float), stream);  // mseg, ssum

    k_sniff<<<1, 256, 0, stream>>>((const int*)edge, iflag);
    k_u<<<1, 128, 0, stream>>>(W, a1, a2, u);
    k_gemm<<<NN / 16, 256, 0, stream>>>(input, W, h);
    k_svec<<<NN / 4, 256, 0, stream>>>(input, p_h, new_h, u, s1, s2, scf, s4);
    k_colscore<<<(NN + 255) / 256, 256, 0, stream>>>(s1, s2, edge_col, row_i, iflag, ec, (unsigned int*)mseg);
    k_expsum<<<(NN + 255) / 256, 256, 0, stream>>>(ec, (const unsigned int*)mseg, row_i, iflag, ssum);
    k_norm<<<(NN + 255) / 256, 256, 0, stream>>>(ec, ssum, row_i, iflag, scf);
    k_cnt<<<NBLK, 512, 0, stream>>>(edge, iflag, cntm);
    k_colscan<<<NB, 1024, 0, stream>>>(cntm, colpre, bcnt);
    k_bscan<<<1, 256, 0, stream>>>(bcnt, bstart, start);
    k_edgeA<<<NBLK, 512, 0, stream>>>((const float2*)scf, s4, edge, row_resort, iflag, bstart, colpre, tmp, out2);
    k_edgeB<<<NB, 512, 0, stream>>>(tmp, bstart, start, pairs);
    k_agg<<<NN / 8, 512, 0, stream>>>(h, pairs, start, ersum, out0);
    k_final<<<2 * NE / 256, 256, 0, stream>>>(edge, iflag, ersum, out2, out1);
}

// Round 9
// 297.429 us; speedup vs baseline: 1.1826x; 1.0448x over previous
//
#include <hip/hip_runtime.h>

#define NN 50000
#define NE 1600000
#define FIN 128
#define FOUT 64
#define ALPHA 0.2f

#define RANGE 256          // destination nodes per bucket
#define NB 196             // ceil(NN / RANGE)
#define EPB 2048           // edges per block in pass A / cnt
#define NBLK 782           // ceil(NE / EPB)

__device__ inline int ldi(const void* p, size_t i, int isi64) {
    int v = isi64 ? (int)((const long long*)p)[i] : ((const int*)p)[i];
    return v < 0 ? 0 : (v >= NN ? NN - 1 : v);  // clamp: no data-dependent OOB
}

// f32 -> bf16 round-to-nearest-even
__device__ inline unsigned short f2bf(float x) {
    unsigned u = __float_as_uint(x);
    return (unsigned short)((u + 0x7FFFu + ((u >> 16) & 1u)) >> 16);
}

// ---------- K0: fused {int-width sniffer | u = W @ {a1l,a1r,a2l,a2r}} ----------
__global__ __launch_bounds__(256) void k_su(const int* __restrict__ edge32, int* __restrict__ iflag,
                                            const float* __restrict__ W, const float* __restrict__ a1,
                                            const float* __restrict__ a2, float* __restrict__ u) {
    if (blockIdx.x == 0) {
        __shared__ int zodd;
        if (threadIdx.x == 0) zodd = 0;
        __syncthreads();
        int z = 0;
        for (int i = threadIdx.x; i < 2048; i += 256)
            if (edge32[2 * i + 1] == 0) z++;    // int64 high words are always 0
        atomicAdd(&zodd, z);
        __syncthreads();
        if (threadIdx.x == 0) *iflag = (zodd > 2000) ? 1 : 0;
    } else {
        int k = threadIdx.x;  // 0..127 active
        if (k < FIN) {
            float u1 = 0.f, u2 = 0.f, u3 = 0.f, u4 = 0.f;
            for (int j = 0; j < FOUT; j++) {
                float w = W[k * FOUT + j];
                u1 += w * a1[j];
                u2 += w * a1[FOUT + j];
                u3 += w * a2[j];
                u4 += w * a2[FOUT + j];
            }
            u[k] = u1; u[128 + k] = u2; u[256 + k] = u3; u[384 + k] = u4;
        }
    }
}

// ---------- K1: h = input @ W  (N x 64, stored bf16 — consumed only by k_agg) ----------
__global__ __launch_bounds__(256) void k_gemm(const float* __restrict__ X,
                                              const float* __restrict__ W,
                                              unsigned short* __restrict__ h) {
    __shared__ float wlds[FIN * FOUT];      // 32 KB
    __shared__ float xlds[4][4][FIN];       // 8 KB
    int tid = threadIdx.x;
    for (int i = tid; i < FIN * FOUT; i += 256) wlds[i] = W[i];
    int wave = tid >> 6, lane = tid & 63;
    int base = blockIdx.x * 16 + wave * 4;  // 3125*16 = 50000 exact
    for (int n0 = 0; n0 < 4; n0++) {
        float2 b = ((const float2*)(X + (size_t)(base + n0) * FIN))[lane];
        xlds[wave][n0][2 * lane] = b.x;
        xlds[wave][n0][2 * lane + 1] = b.y;
    }
    __syncthreads();
    float a0 = 0.f, a1v = 0.f, a2v = 0.f, a3 = 0.f;
    for (int k = 0; k < FIN; k++) {
        float w = wlds[k * FOUT + lane];
        a0  += xlds[wave][0][k] * w;
        a1v += xlds[wave][1][k] * w;
        a2v += xlds[wave][2][k] * w;
        a3  += xlds[wave][3][k] * w;
    }
    h[(size_t)(base + 0) * FOUT + lane] = f2bf(a0);
    h[(size_t)(base + 1) * FOUT + lane] = f2bf(a1v);
    h[(size_t)(base + 2) * FOUT + lane] = f2bf(a2v);
    h[(size_t)(base + 3) * FOUT + lane] = f2bf(a3);
}

// ---------- K1b: fused {per-node score scalars | per-block bucket counts} ----------
// Blocks [0,12500): svec (one wave per node). Blocks [12500,13282): cnt rows.
// cnt (~7 us of edge streaming) hides inside svec's 77 MB input streaming.
__global__ __launch_bounds__(256) void k_svec_cnt(const float* __restrict__ input,
                                                  const float* __restrict__ p_h,
                                                  const float* __restrict__ new_h,
                                                  const float* __restrict__ u,
                                                  float* __restrict__ s1, float* __restrict__ s2,
                                                  float* __restrict__ sc /* float2 as float* */,
                                                  float* __restrict__ s4,
                                                  const void* __restrict__ edge,
                                                  const int* __restrict__ iflag,
                                                  int* __restrict__ cntm) {
    __shared__ int hist[NB];
    int tid = threadIdx.x;
    if (blockIdx.x < 12500) {
        int lane = tid & 63;
        int v = blockIdx.x * 4 + (tid >> 6);
        size_t row = (size_t)v * FIN;
        float2 bi = ((const float2*)(input + row))[lane];
        float2 bp = ((const float2*)(p_h   + row))[lane];
        float2 bn = ((const float2*)(new_h + row))[lane];
        float p1 = bi.x * u[2 * lane]       + bi.y * u[2 * lane + 1];
        float p2 = bp.x * u[128 + 2 * lane] + bp.y * u[128 + 2 * lane + 1];
        float p3 = bn.x * u[256 + 2 * lane] + bn.y * u[256 + 2 * lane + 1];
        float p4 = bi.x * u[384 + 2 * lane] + bi.y * u[384 + 2 * lane + 1];
#pragma unroll
        for (int off = 32; off > 0; off >>= 1) {
            p1 += __shfl_down(p1, off, 64);
            p2 += __shfl_down(p2, off, 64);
            p3 += __shfl_down(p3, off, 64);
            p4 += __shfl_down(p4, off, 64);
        }
        if (lane == 0) { s1[v] = p1; s2[v] = p2; sc[2 * v] = p3; s4[v] = p4; }
    } else {
        int cb = blockIdx.x - 12500;                  // 0..781
        for (int t = tid; t < NB; t += 256) hist[t] = 0;
        __syncthreads();
        int i64 = *iflag;
        int base = cb * EPB;
#pragma unroll
        for (int k = 0; k < 8; k++) {
            int e = base + k * 256 + tid;
            if (e < NE) atomicAdd(&hist[ldi(edge, e, i64) >> 8], 1);
        }
        __syncthreads();
        for (int t = tid; t < NB; t += 256)
            cntm[cb * NB + t] = hist[t];              // plain coalesced row store
    }
}

// ---------- K2: col score + exp + segment max ----------
__global__ void k_colscore(const float* __restrict__ s1, const float* __restrict__ s2,
                           const void* __restrict__ edge_col, const void* __restrict__ row_i,
                           const int* __restrict__ iflag,
                           float* __restrict__ ec, unsigned int* __restrict__ m) {
    int i = blockIdx.x * 256 + threadIdx.x;
    if (i >= NN) return;
    int i64 = *iflag;
    float cs = s1[ldi(edge_col, i, i64)] + s2[i];
    float l = cs > 0.f ? cs : ALPHA * cs;
    float e = expf(-l);                // > 0 always
    ec[i] = e;
    atomicMax(&m[ldi(row_i, i, i64)], __float_as_uint(e));  // init 0, e>0 -> valid
}

// ---------- K3: ex = exp(ec - m) in place; segment sum ----------
__global__ void k_expsum(float* __restrict__ ec, const unsigned int* __restrict__ m,
                         const void* __restrict__ row_i, const int* __restrict__ iflag,
                         float* __restrict__ ssum) {
    int i = blockIdx.x * 256 + threadIdx.x;
    if (i >= NN) return;
    int r = ldi(row_i, i, *iflag);
    float e = expf(ec[i] - __uint_as_float(m[r]));
    ec[i] = e;
    atomicAdd(&ssum[r], e);
}

// ---------- K4: normalize -> sc[i].y = ecs ----------
__global__ void k_norm(const float* __restrict__ ex, const float* __restrict__ ssum,
                       const void* __restrict__ row_i, const int* __restrict__ iflag,
                       float* __restrict__ sc /* float2 as float* */) {
    int i = blockIdx.x * 256 + threadIdx.x;
    if (i >= NN) return;
    sc[2 * i + 1] = ex[i] / (ssum[ldi(row_i, i, *iflag)] + 1e-16f);
}

// ---------- K5b1: per-bucket column scan over 782 blocks -> colpre, bcnt ----------
__global__ __launch_bounds__(1024) void k_colscan(const int* __restrict__ cntm,
                                                  int* __restrict__ colpre,
                                                  int* __restrict__ bcnt) {
    __shared__ int s[1024];
    int b = blockIdx.x, tid = threadIdx.x;
    int x = (tid < NBLK) ? cntm[(size_t)tid * NB + b] : 0;
    s[tid] = x;
    __syncthreads();
    for (int off = 1; off < 1024; off <<= 1) {
        int t = (tid >= off) ? s[tid - off] : 0;
        __syncthreads();
        s[tid] += t;
        __syncthreads();
    }
    if (tid < NBLK) colpre[(size_t)tid * NB + b] = s[tid] - x;  // exclusive within column
    if (tid == 1023) bcnt[b] = s[1023];                         // column total
}

// ---------- K5b2: scan 196 bucket totals -> bstart; sentinels ----------
__global__ __launch_bounds__(256) void k_bscan(const int* __restrict__ bcnt,
                                               int* __restrict__ bstart,
                                               int* __restrict__ start) {
    __shared__ int s[256];
    int tid = threadIdx.x;
    int x = (tid < NB) ? bcnt[tid] : 0;
    s[tid] = x;
    __syncthreads();
    for (int off = 1; off < 256; off <<= 1) {
        int t = (tid >= off) ? s[tid - off] : 0;
        __syncthreads();
        s[tid] += t;
        __syncthreads();
    }
    if (tid < NB) bstart[tid] = s[tid] - x;
    if (tid == 0) { bstart[NB] = NE; start[NN] = NE; }
}

// ---------- K5c pass A: per-edge score + coarse scatter, deterministic offsets ----------
__global__ __launch_bounds__(512) void k_edgeA(const float2* __restrict__ sc, const float* __restrict__ s4,
                                               const void* __restrict__ edge, const void* __restrict__ row_resort,
                                               const int* __restrict__ iflag,
                                               const int* __restrict__ bstart, const int* __restrict__ colpre,
                                               uint2* __restrict__ tmp,
                                               float* __restrict__ edge_e /* = out2 */) {
    __shared__ int hist[NB];
    __shared__ int bbase[NB];
    int tid = threadIdx.x;
    for (int t = tid; t < NB; t += 512) hist[t] = 0;
    __syncthreads();
    int i64 = *iflag;
    int base = blockIdx.x * EPB;
    unsigned int key[4]; float val[4]; int rk[4], bk[4];
#pragma unroll
    for (int k = 0; k < 4; k++) {
        int e = base + k * 512 + tid;
        bk[k] = -1;
        if (e < NE) {
            int e0 = ldi(edge, e, i64);
            int e1 = ldi(edge, (size_t)NE + e, i64);
            int rr = ldi(row_resort, e, i64);
            float2 c = sc[rr];                         // {s3, ecs} one gather
            float rs = c.x + s4[e1];
            float l = rs > 0.f ? rs : ALPHA * rs;
            float ee = expf(-l) * c.y;
            edge_e[e] = ee;                           // numerator for out2 (sequential)
            key[k] = (unsigned int)e0 | ((unsigned int)e1 << 16);  // both < 65536
            val[k] = ee;
            bk[k] = e0 >> 8;                          // bucket = e0 / RANGE
            rk[k] = atomicAdd(&hist[bk[k]], 1);       // rank within (block, bucket)
        }
    }
    __syncthreads();
    for (int t = tid; t < NB; t += 512)
        bbase[t] = bstart[t] + colpre[(size_t)blockIdx.x * NB + t];  // plain load
    __syncthreads();
#pragma unroll
    for (int k = 0; k < 4; k++)
        if (bk[k] >= 0)
            tmp[bbase[bk[k]] + rk[k]] = make_uint2(key[k], __float_as_uint(val[k]));
}

// ---------- K5c pass B: per-node offsets + fine scatter, L2-resident ----------
__global__ __launch_bounds__(512) void k_edgeB(const uint2* __restrict__ tmp,
                                               const int* __restrict__ bstart,
                                               int* __restrict__ start,
                                               float2* __restrict__ pairs) {
    __shared__ int cnt[RANGE];
    __shared__ int s[RANGE];
    __shared__ int cur[RANGE];
    int b = blockIdx.x;
    int tid = threadIdx.x;
    int v0 = b * RANGE;
    if (tid < RANGE) cnt[tid] = 0;
    __syncthreads();
    int lo = bstart[b], hi = bstart[b + 1];
    for (int i = lo + tid; i < hi; i += 512)
        atomicAdd(&cnt[tmp[i].x & 0xFFu], 1);         // e0 & 255 == e0 - v0
    __syncthreads();
    if (tid < RANGE) s[tid] = cnt[tid];
    __syncthreads();
    for (int off = 1; off < RANGE; off <<= 1) {
        int t = 0;
        if (tid < RANGE && tid >= off) t = s[tid - off];
        __syncthreads();
        if (tid < RANGE) s[tid] += t;
        __syncthreads();
    }
    if (tid < RANGE) {
        int g = lo + s[tid] - cnt[tid];               // exclusive prefix + bucket base
        cur[tid] = g;
        int v = v0 + tid;
        if (v < NN) start[v] = g;
    }
    __syncthreads();
    for (int i = lo + tid; i < hi; i += 512) {
        uint2 r = tmp[i];
        int pos = atomicAdd(&cur[r.x & 0xFFu], 1);    // LDS atomic
        pairs[pos] = make_float2(__int_as_float((int)(r.x >> 16)), __uint_as_float(r.y));
    }
}

// ---------- K6: gather-aggregate; 8 edge slots x 8 feats/lane (uint4 gathers) ----------
// One wave per node. q=lane>>3 edge slot, fq=lane&7 feature octet. Main loop is
// bounds-check-free (full 16-edge groups); guarded tail runs at most once.
// ~3 insts/edge vs ~5 in the 4-slot layout. Reduction: shfl_xor over q bits.
__global__ __launch_bounds__(512) void k_agg(const unsigned short* __restrict__ h,
                                             const float2* __restrict__ pairs,
                                             const int* __restrict__ start,
                                             float* __restrict__ ersum,
                                             float* __restrict__ out0) {
    int lane = threadIdx.x & 63;
    int q  = lane >> 3;                // edge slot 0..7
    int fq = lane & 7;                 // feature octet: feats 8fq..8fq+7
    int v = blockIdx.x * 8 + (threadIdx.x >> 6);      // 6250*8 = NN exact
    int a = start[v], b = start[v + 1];
    float acc0 = 0.f, acc1 = 0.f, acc2 = 0.f, acc3 = 0.f;
    float acc4 = 0.f, acc5 = 0.f, acc6 = 0.f, acc7 = 0.f, rs = 0.f;
    int bfull = a + ((b - a) & ~15);
    int j = a;
    for (; j < bfull; j += 16) {                      // no bounds checks
        float2 pA = pairs[j + q];
        float2 pB = pairs[j + 8 + q];
        uint4 hA = *(const uint4*)(h + (((size_t)__float_as_int(pA.x)) << 6) + 8 * fq);
        uint4 hB = *(const uint4*)(h + (((size_t)__float_as_int(pB.x)) << 6) + 8 * fq);
        acc0 += pA.y * __uint_as_float(hA.x << 16);
        acc1 += pA.y * __uint_as_float(hA.x & 0xFFFF0000u);
        acc2 += pA.y * __uint_as_float(hA.y << 16);
        acc3 += pA.y * __uint_as_float(hA.y & 0xFFFF0000u);
        acc4 += pA.y * __uint_as_float(hA.z << 16);
        acc5 += pA.y * __uint_as_float(hA.z & 0xFFFF0000u);
        acc6 += pA.y * __uint_as_float(hA.w << 16);
        acc7 += pA.y * __uint_as_float(hA.w & 0xFFFF0000u);
        acc0 += pB.y * __uint_as_float(hB.x << 16);
        acc1 += pB.y * __uint_as_float(hB.x & 0xFFFF0000u);
        acc2 += pB.y * __uint_as_float(hB.y << 16);
        acc3 += pB.y * __uint_as_float(hB.y & 0xFFFF0000u);
        acc4 += pB.y * __uint_as_float(hB.z << 16);
        acc5 += pB.y * __uint_as_float(hB.z & 0xFFFF0000u);
        acc6 += pB.y * __uint_as_float(hB.w << 16);
        acc7 += pB.y * __uint_as_float(hB.w & 0xFFFF0000u);
        rs += pA.y + pB.y;
    }
    if (j < b) {                                      // guarded tail, single pass
        int eA = j + q, eB = j + 8 + q;
        float2 pA = (eA < b) ? pairs[eA] : make_float2(__int_as_float(0), 0.f);
        float2 pB = (eB < b) ? pairs[eB] : make_float2(__int_as_float(0), 0.f);
        uint4 hA = *(const uint4*)(h + (((size_t)__float_as_int(pA.x)) << 6) + 8 * fq);
        uint4 hB = *(const uint4*)(h + (((size_t)__float_as_int(pB.x)) << 6) + 8 * fq);
        acc0 += pA.y * __uint_as_float(hA.x << 16);
        acc1 += pA.y * __uint_as_float(hA.x & 0xFFFF0000u);
        acc2 += pA.y * __uint_as_float(hA.y << 16);
        acc3 += pA.y * __uint_as_float(hA.y & 0xFFFF0000u);
        acc4 += pA.y * __uint_as_float(hA.z << 16);
        acc5 += pA.y * __uint_as_float(hA.z & 0xFFFF0000u);
        acc6 += pA.y * __uint_as_float(hA.w << 16);
        acc7 += pA.y * __uint_as_float(hA.w & 0xFFFF0000u);
        acc0 += pB.y * __uint_as_float(hB.x << 16);
        acc1 += pB.y * __uint_as_float(hB.x & 0xFFFF0000u);
        acc2 += pB.y * __uint_as_float(hB.y << 16);
        acc3 += pB.y * __uint_as_float(hB.y & 0xFFFF0000u);
        acc4 += pB.y * __uint_as_float(hB.z << 16);
        acc5 += pB.y * __uint_as_float(hB.z & 0xFFFF0000u);
        acc6 += pB.y * __uint_as_float(hB.w << 16);
        acc7 += pB.y * __uint_as_float(hB.w & 0xFFFF0000u);
        rs += pA.y + pB.y;
    }
#pragma unroll
    for (int off = 8; off <= 32; off <<= 1) {         // reduce across edge slots
        acc0 += __shfl_xor(acc0, off, 64);
        acc1 += __shfl_xor(acc1, off, 64);
        acc2 += __shfl_xor(acc2, off, 64);
        acc3 += __shfl_xor(acc3, off, 64);
        acc4 += __shfl_xor(acc4, off, 64);
        acc5 += __shfl_xor(acc5, off, 64);
        acc6 += __shfl_xor(acc6, off, 64);
        acc7 += __shfl_xor(acc7, off, 64);
        rs   += __shfl_xor(rs, off, 64);
    }
    if (q == 0) {
        rs += (rs == 0.f) ? 1.f : 0.f;                // empty-segment fixup (ee>0 otherwise)
        float4 o1, o2;
        o1.x = acc0 / rs; o1.y = acc1 / rs; o1.z = acc2 / rs; o1.w = acc3 / rs;
        o2.x = acc4 / rs; o2.y = acc5 / rs; o2.z = acc6 / rs; o2.w = acc7 / rs;
        o1.x = o1.x > 0.f ? o1.x : expm1f(o1.x);
        o1.y = o1.y > 0.f ? o1.y : expm1f(o1.y);
        o1.z = o1.z > 0.f ? o1.z : expm1f(o1.z);
        o1.w = o1.w > 0.f ? o1.w : expm1f(o1.w);
        o2.x = o2.x > 0.f ? o2.x : expm1f(o2.x);
        o2.y = o2.y > 0.f ? o2.y : expm1f(o2.y);
        o2.z = o2.z > 0.f ? o2.z : expm1f(o2.z);
        o2.w = o2.w > 0.f ? o2.w : expm1f(o2.w);
        float4* dst = (float4*)(out0 + (size_t)v * FOUT + 8 * fq);
        dst[0] = o1;
        dst[1] = o2;
        if (fq == 0) ersum[v] = rs;                   // fixed rowsum, plain store
    }
}

// ---------- K7: out1 = float(edge) AND out2 /= ersum[e0] (fused, runs LAST) ----------
__global__ __launch_bounds__(256) void k_final(const void* __restrict__ edge, const int* __restrict__ iflag,
                                               const float* __restrict__ ersum,
                                               float* __restrict__ out2, float* __restrict__ out1) {
    int i = blockIdx.x * 256 + threadIdx.x;           // 12500*256 = 2*NE exact
    int i64 = *iflag;
    int v = i64 ? (int)((const long long*)edge)[i] : ((const int*)edge)[i];
    out1[i] = (float)v;
    if (i < NE) {                                     // edge[0..NE) is row 0 = e0
        int e0 = v < 0 ? 0 : (v >= NN ? NN - 1 : v);
        out2[i] = out2[i] / ersum[e0];
    }
}

extern "C" void kernel_launch(void* const* d_in, const int* in_sizes, int n_in,
                              void* d_out, int out_size, void* d_ws, size_t ws_size,
                              hipStream_t stream) {
    // Resolve inputs by element count (all distinct).
    int ix[3] = {0, 1, 2}; int nx = 0;
    int iE = 3, iCol = 4, iRowI = 5, iRes = 6, iW = 8, iA1 = 9, iA2 = 10;
    bool a1seen = false;
    for (int i = 0; i < n_in; i++) {
        int s = in_sizes[i];
        if (s == NN * FIN) { if (nx < 3) ix[nx++] = i; }
        else if (s == 2 * NE) iE = i;
        else if (s == 2 * NN) iCol = i;
        else if (s == NN) iRowI = i;
        else if (s == NE) iRes = i;
        else if (s == FIN * FOUT) iW = i;
        else if (s == 2 * FOUT) { if (!a1seen) { iA1 = i; a1seen = true; } else iA2 = i; }
    }
    const float* input = (const float*)d_in[ix[0]];
    const float* p_h   = (const float*)d_in[ix[1]];
    const float* new_h = (const float*)d_in[ix[2]];
    const void* edge       = d_in[iE];
    const void* edge_col   = d_in[iCol];
    const void* row_i      = d_in[iRowI];
    const void* row_resort = d_in[iRes];
    const float* W  = (const float*)d_in[iW];
    const float* a1 = (const float*)d_in[iA1];
    const float* a2 = (const float*)d_in[iA2];

    // Outputs are FLOAT32, concatenated.
    float* out0 = (float*)d_out;                      // N*FOUT
    float* out1 = out0 + (size_t)NN * FOUT;           // 2*NE
    float* out2 = out1 + (size_t)2 * NE;              // NE (edge_e numerator, then in-place divide)

    // Coarse-scatter scratch: out1 region is free until k_final (last kernel).
    uint2* tmp = (uint2*)out1;

    // ws layout (~29 MB; h region reserved as NN*FOUT floats, used as bf16)
    unsigned short* h = (unsigned short*)d_ws;        // NN*FOUT bf16 (6.4 MB used)
    float2* pairs  = (float2*)((float*)d_ws + (size_t)NN * FOUT); // NE float2 (12.8 MB)
    float*  s1     = (float*)(pairs + NE);
    float*  s2     = s1 + NN;
    float*  s4     = s2 + NN;
    float*  ec     = s4 + NN;                         // reused in place as ex
    float*  scf    = ec + NN;                         // float2[NN]: {s3, ecs}
    float*  mseg   = scf + 2 * (size_t)NN;            // zeroed (atomicMax uint bits)
    float*  ssum   = mseg + NN;                       // zeroed
    int*    bcnt   = (int*)(ssum + NN);               // NB
    int*    start  = bcnt + NB;                       // NN+1 (sentinel)
    int*    bstart = start + NN + 1;                  // NB+1
    int*    cntm   = bstart + NB + 1;                 // NBLK*NB (613 KB)
    int*    colpre = cntm + (size_t)NBLK * NB;        // NBLK*NB (613 KB)
    float*  ersum  = (float*)(colpre + (size_t)NBLK * NB);  // NN
    float*  u      = ersum + NN;                      // 512
    int*    iflag  = (int*)(u + 512);

    hipMemsetAsync(mseg, 0, (size_t)2 * NN * sizeof(float), stream);  // mseg, ssum

    k_su<<<2, 256, 0, stream>>>((const int*)edge, iflag, W, a1, a2, u);
    k_gemm<<<NN / 16, 256, 0, stream>>>(input, W, h);
    k_svec_cnt<<<12500 + NBLK, 256, 0, stream>>>(input, p_h, new_h, u, s1, s2, scf, s4,
                                                 edge, iflag, cntm);
    k_colscore<<<(NN + 255) / 256, 256, 0, stream>>>(s1, s2, edge_col, row_i, iflag, ec, (unsigned int*)mseg);
    k_expsum<<<(NN + 255) / 256, 256, 0, stream>>>(ec, (const unsigned int*)mseg, row_i, iflag, ssum);
    k_norm<<<(NN + 255) / 256, 256, 0, stream>>>(ec, ssum, row_i, iflag, scf);
    k_colscan<<<NB, 1024, 0, stream>>>(cntm, colpre, bcnt);
    k_bscan<<<1, 256, 0, stream>>>(bcnt, bstart, start);
    k_edgeA<<<NBLK, 512, 0, stream>>>((const float2*)scf, s4, edge, row_resort, iflag, bstart, colpre, tmp, out2);
    k_edgeB<<<NB, 512, 0, stream>>>(tmp, bstart, start, pairs);
    k_agg<<<NN / 8, 512, 0, stream>>>(h, pairs, start, ersum, out0);
    k_final<<<2 * NE / 256, 256, 0, stream>>>(edge, iflag, ersum, out2, out1);
}

// Round 10
// 291.050 us; speedup vs baseline: 1.2086x; 1.0219x over previous
//
#include <hip/hip_runtime.h>

#define NN 50000
#define NE 1600000
#define FIN 128
#define FOUT 64
#define ALPHA 0.2f

#define RANGE 256          // destination nodes per bucket
#define NB 196             // ceil(NN / RANGE)
#define EPB 2048           // edges per block in pass A / cnt
#define NBLK 782           // ceil(NE / EPB)

__device__ inline int ldi(const void* p, size_t i, int isi64) {
    int v = isi64 ? (int)((const long long*)p)[i] : ((const int*)p)[i];
    return v < 0 ? 0 : (v >= NN ? NN - 1 : v);  // clamp: no data-dependent OOB
}

// f32 -> bf16 round-to-nearest-even
__device__ inline unsigned short f2bf(float x) {
    unsigned u = __float_as_uint(x);
    return (unsigned short)((u + 0x7FFFu + ((u >> 16) & 1u)) >> 16);
}

// ---------- K0: fused {int-width sniffer | u = W @ {a1l,a1r,a2l,a2r}} ----------
__global__ __launch_bounds__(256) void k_su(const int* __restrict__ edge32, int* __restrict__ iflag,
                                            const float* __restrict__ W, const float* __restrict__ a1,
                                            const float* __restrict__ a2, float* __restrict__ u) {
    if (blockIdx.x == 0) {
        __shared__ int zodd;
        if (threadIdx.x == 0) zodd = 0;
        __syncthreads();
        int z = 0;
        for (int i = threadIdx.x; i < 2048; i += 256)
            if (edge32[2 * i + 1] == 0) z++;    // int64 high words are always 0
        atomicAdd(&zodd, z);
        __syncthreads();
        if (threadIdx.x == 0) *iflag = (zodd > 2000) ? 1 : 0;
    } else {
        int k = threadIdx.x;  // 0..127 active
        if (k < FIN) {
            float u1 = 0.f, u2 = 0.f, u3 = 0.f, u4 = 0.f;
            for (int j = 0; j < FOUT; j++) {
                float w = W[k * FOUT + j];
                u1 += w * a1[j];
                u2 += w * a1[FOUT + j];
                u3 += w * a2[j];
                u4 += w * a2[FOUT + j];
            }
            u[k] = u1; u[128 + k] = u2; u[256 + k] = u3; u[384 + k] = u4;
        }
    }
}

// ---------- K1: h = input @ W  (N x 64, stored bf16 — consumed only by k_agg) ----------
__global__ __launch_bounds__(256) void k_gemm(const float* __restrict__ X,
                                              const float* __restrict__ W,
                                              unsigned short* __restrict__ h) {
    __shared__ float wlds[FIN * FOUT];      // 32 KB
    __shared__ float xlds[4][4][FIN];       // 8 KB
    int tid = threadIdx.x;
    for (int i = tid; i < FIN * FOUT; i += 256) wlds[i] = W[i];
    int wave = tid >> 6, lane = tid & 63;
    int base = blockIdx.x * 16 + wave * 4;  // 3125*16 = 50000 exact
    for (int n0 = 0; n0 < 4; n0++) {
        float2 b = ((const float2*)(X + (size_t)(base + n0) * FIN))[lane];
        xlds[wave][n0][2 * lane] = b.x;
        xlds[wave][n0][2 * lane + 1] = b.y;
    }
    __syncthreads();
    float a0 = 0.f, a1v = 0.f, a2v = 0.f, a3 = 0.f;
    for (int k = 0; k < FIN; k++) {
        float w = wlds[k * FOUT + lane];
        a0  += xlds[wave][0][k] * w;
        a1v += xlds[wave][1][k] * w;
        a2v += xlds[wave][2][k] * w;
        a3  += xlds[wave][3][k] * w;
    }
    h[(size_t)(base + 0) * FOUT + lane] = f2bf(a0);
    h[(size_t)(base + 1) * FOUT + lane] = f2bf(a1v);
    h[(size_t)(base + 2) * FOUT + lane] = f2bf(a2v);
    h[(size_t)(base + 3) * FOUT + lane] = f2bf(a3);
}

// ---------- K1b: fused {per-node score scalars | per-block bucket counts} ----------
__global__ __launch_bounds__(256) void k_svec_cnt(const float* __restrict__ input,
                                                  const float* __restrict__ p_h,
                                                  const float* __restrict__ new_h,
                                                  const float* __restrict__ u,
                                                  float* __restrict__ s1, float* __restrict__ s2,
                                                  float* __restrict__ sc /* float2 as float* */,
                                                  float* __restrict__ s4,
                                                  const void* __restrict__ edge,
                                                  const int* __restrict__ iflag,
                                                  int* __restrict__ cntm) {
    __shared__ int hist[NB];
    int tid = threadIdx.x;
    if (blockIdx.x < 12500) {
        int lane = tid & 63;
        int v = blockIdx.x * 4 + (tid >> 6);
        size_t row = (size_t)v * FIN;
        float2 bi = ((const float2*)(input + row))[lane];
        float2 bp = ((const float2*)(p_h   + row))[lane];
        float2 bn = ((const float2*)(new_h + row))[lane];
        float p1 = bi.x * u[2 * lane]       + bi.y * u[2 * lane + 1];
        float p2 = bp.x * u[128 + 2 * lane] + bp.y * u[128 + 2 * lane + 1];
        float p3 = bn.x * u[256 + 2 * lane] + bn.y * u[256 + 2 * lane + 1];
        float p4 = bi.x * u[384 + 2 * lane] + bi.y * u[384 + 2 * lane + 1];
#pragma unroll
        for (int off = 32; off > 0; off >>= 1) {
            p1 += __shfl_down(p1, off, 64);
            p2 += __shfl_down(p2, off, 64);
            p3 += __shfl_down(p3, off, 64);
            p4 += __shfl_down(p4, off, 64);
        }
        if (lane == 0) { s1[v] = p1; s2[v] = p2; sc[2 * v] = p3; s4[v] = p4; }
    } else {
        int cb = blockIdx.x - 12500;                  // 0..781
        for (int t = tid; t < NB; t += 256) hist[t] = 0;
        __syncthreads();
        int i64 = *iflag;
        int base = cb * EPB;
#pragma unroll
        for (int k = 0; k < 8; k++) {
            int e = base + k * 256 + tid;
            if (e < NE) atomicAdd(&hist[ldi(edge, e, i64) >> 8], 1);
        }
        __syncthreads();
        for (int t = tid; t < NB; t += 256)
            cntm[cb * NB + t] = hist[t];              // plain coalesced row store
    }
}

// ---------- K2: col score + exp + segment max ----------
__global__ void k_colscore(const float* __restrict__ s1, const float* __restrict__ s2,
                           const void* __restrict__ edge_col, const void* __restrict__ row_i,
                           const int* __restrict__ iflag,
                           float* __restrict__ ec, unsigned int* __restrict__ m) {
    int i = blockIdx.x * 256 + threadIdx.x;
    if (i >= NN) return;
    int i64 = *iflag;
    float cs = s1[ldi(edge_col, i, i64)] + s2[i];
    float l = cs > 0.f ? cs : ALPHA * cs;
    float e = expf(-l);                // > 0 always
    ec[i] = e;
    atomicMax(&m[ldi(row_i, i, i64)], __float_as_uint(e));  // init 0, e>0 -> valid
}

// ---------- K3: ex = exp(ec - m) in place; segment sum ----------
__global__ void k_expsum(float* __restrict__ ec, const unsigned int* __restrict__ m,
                         const void* __restrict__ row_i, const int* __restrict__ iflag,
                         float* __restrict__ ssum) {
    int i = blockIdx.x * 256 + threadIdx.x;
    if (i >= NN) return;
    int r = ldi(row_i, i, *iflag);
    float e = expf(ec[i] - __uint_as_float(m[r]));
    ec[i] = e;
    atomicAdd(&ssum[r], e);
}

// ---------- K4: normalize -> sc[i].y = ecs ----------
__global__ void k_norm(const float* __restrict__ ex, const float* __restrict__ ssum,
                       const void* __restrict__ row_i, const int* __restrict__ iflag,
                       float* __restrict__ sc /* float2 as float* */) {
    int i = blockIdx.x * 256 + threadIdx.x;
    if (i >= NN) return;
    sc[2 * i + 1] = ex[i] / (ssum[ldi(row_i, i, *iflag)] + 1e-16f);
}

// ---------- K5b1: per-bucket column scan over 782 blocks -> colpre, bcnt ----------
__global__ __launch_bounds__(1024) void k_colscan(const int* __restrict__ cntm,
                                                  int* __restrict__ colpre,
                                                  int* __restrict__ bcnt) {
    __shared__ int s[1024];
    int b = blockIdx.x, tid = threadIdx.x;
    int x = (tid < NBLK) ? cntm[(size_t)tid * NB + b] : 0;
    s[tid] = x;
    __syncthreads();
    for (int off = 1; off < 1024; off <<= 1) {
        int t = (tid >= off) ? s[tid - off] : 0;
        __syncthreads();
        s[tid] += t;
        __syncthreads();
    }
    if (tid < NBLK) colpre[(size_t)tid * NB + b] = s[tid] - x;  // exclusive within column
    if (tid == 1023) bcnt[b] = s[1023];                         // column total
}

// ---------- K5b2: scan 196 bucket totals -> bstart; sentinels ----------
__global__ __launch_bounds__(256) void k_bscan(const int* __restrict__ bcnt,
                                               int* __restrict__ bstart,
                                               int* __restrict__ start) {
    __shared__ int s[256];
    int tid = threadIdx.x;
    int x = (tid < NB) ? bcnt[tid] : 0;
    s[tid] = x;
    __syncthreads();
    for (int off = 1; off < 256; off <<= 1) {
        int t = (tid >= off) ? s[tid - off] : 0;
        __syncthreads();
        s[tid] += t;
        __syncthreads();
    }
    if (tid < NB) bstart[tid] = s[tid] - x;
    if (tid == 0) { bstart[NB] = NE; start[NN] = NE; }
}

// ---------- K5c pass A: per-edge score + coarse scatter, deterministic offsets ----------
__global__ __launch_bounds__(512) void k_edgeA(const float2* __restrict__ sc, const float* __restrict__ s4,
                                               const void* __restrict__ edge, const void* __restrict__ row_resort,
                                               const int* __restrict__ iflag,
                                               const int* __restrict__ bstart, const int* __restrict__ colpre,
                                               uint2* __restrict__ tmp,
                                               float* __restrict__ edge_e /* = out2 */) {
    __shared__ int hist[NB];
    __shared__ int bbase[NB];
    int tid = threadIdx.x;
    for (int t = tid; t < NB; t += 512) hist[t] = 0;
    __syncthreads();
    int i64 = *iflag;
    int base = blockIdx.x * EPB;
    unsigned int key[4]; float val[4]; int rk[4], bk[4];
#pragma unroll
    for (int k = 0; k < 4; k++) {
        int e = base + k * 512 + tid;
        bk[k] = -1;
        if (e < NE) {
            int e0 = ldi(edge, e, i64);
            int e1 = ldi(edge, (size_t)NE + e, i64);
            int rr = ldi(row_resort, e, i64);
            float2 c = sc[rr];                         // {s3, ecs} one gather
            float rs = c.x + s4[e1];
            float l = rs > 0.f ? rs : ALPHA * rs;
            float ee = expf(-l) * c.y;
            edge_e[e] = ee;                           // numerator for out2 (sequential)
            key[k] = (unsigned int)e0 | ((unsigned int)e1 << 16);  // both < 65536
            val[k] = ee;
            bk[k] = e0 >> 8;                          // bucket = e0 / RANGE
            rk[k] = atomicAdd(&hist[bk[k]], 1);       // rank within (block, bucket)
        }
    }
    __syncthreads();
    for (int t = tid; t < NB; t += 512)
        bbase[t] = bstart[t] + colpre[(size_t)blockIdx.x * NB + t];  // plain load
    __syncthreads();
#pragma unroll
    for (int k = 0; k < 4; k++)
        if (bk[k] >= 0)
            tmp[bbase[bk[k]] + rk[k]] = make_uint2(key[k], __float_as_uint(val[k]));
}

// ---------- K5c pass B: per-node offsets + fine scatter, L2-resident ----------
__global__ __launch_bounds__(512) void k_edgeB(const uint2* __restrict__ tmp,
                                               const int* __restrict__ bstart,
                                               int* __restrict__ start,
                                               float2* __restrict__ pairs) {
    __shared__ int cnt[RANGE];
    __shared__ int s[RANGE];
    __shared__ int cur[RANGE];
    int b = blockIdx.x;
    int tid = threadIdx.x;
    int v0 = b * RANGE;
    if (tid < RANGE) cnt[tid] = 0;
    __syncthreads();
    int lo = bstart[b], hi = bstart[b + 1];
    for (int i = lo + tid; i < hi; i += 512)
        atomicAdd(&cnt[tmp[i].x & 0xFFu], 1);         // e0 & 255 == e0 - v0
    __syncthreads();
    if (tid < RANGE) s[tid] = cnt[tid];
    __syncthreads();
    for (int off = 1; off < RANGE; off <<= 1) {
        int t = 0;
        if (tid < RANGE && tid >= off) t = s[tid - off];
        __syncthreads();
        if (tid < RANGE) s[tid] += t;
        __syncthreads();
    }
    if (tid < RANGE) {
        int g = lo + s[tid] - cnt[tid];               // exclusive prefix + bucket base
        cur[tid] = g;
        int v = v0 + tid;
        if (v < NN) start[v] = g;
    }
    __syncthreads();
    for (int i = lo + tid; i < hi; i += 512) {
        uint2 r = tmp[i];
        int pos = atomicAdd(&cur[r.x & 0xFFu], 1);    // LDS atomic
        pairs[pos] = make_float2(__int_as_float((int)(r.x >> 16)), __uint_as_float(r.y));
    }
}

// ---------- K6: gather-aggregate; 8 edge slots x 8 feats/lane; 1-result/lane epilogue ----------
// Main loop unchanged from round 9. Epilogue: butterfly over q bits, then each
// lane KEEPS acc[lane>>3] (feature 8*(lane&7) + (lane>>3), a bijective bit-swap
// permutation of 0..63) -> ONE rcp-div, ONE expm1, one 64-lane store per wave,
// instead of 8 divides + 8 expm1 issued wave-wide for 8 surviving lanes.
__global__ __launch_bounds__(512) void k_agg(const unsigned short* __restrict__ h,
                                             const float2* __restrict__ pairs,
                                             const int* __restrict__ start,
                                             float* __restrict__ ersum,
                                             float* __restrict__ out0) {
    int lane = threadIdx.x & 63;
    int q  = lane >> 3;                // edge slot 0..7
    int fq = lane & 7;                 // feature octet: feats 8fq..8fq+7
    int v = blockIdx.x * 8 + (threadIdx.x >> 6);      // 6250*8 = NN exact
    int a = start[v], b = start[v + 1];
    float acc0 = 0.f, acc1 = 0.f, acc2 = 0.f, acc3 = 0.f;
    float acc4 = 0.f, acc5 = 0.f, acc6 = 0.f, acc7 = 0.f, rs = 0.f;
    int bfull = a + ((b - a) & ~15);
    int j = a;
    for (; j < bfull; j += 16) {                      // no bounds checks
        float2 pA = pairs[j + q];
        float2 pB = pairs[j + 8 + q];
        uint4 hA = *(const uint4*)(h + (((size_t)__float_as_int(pA.x)) << 6) + 8 * fq);
        uint4 hB = *(const uint4*)(h + (((size_t)__float_as_int(pB.x)) << 6) + 8 * fq);
        acc0 += pA.y * __uint_as_float(hA.x << 16);
        acc1 += pA.y * __uint_as_float(hA.x & 0xFFFF0000u);
        acc2 += pA.y * __uint_as_float(hA.y << 16);
        acc3 += pA.y * __uint_as_float(hA.y & 0xFFFF0000u);
        acc4 += pA.y * __uint_as_float(hA.z << 16);
        acc5 += pA.y * __uint_as_float(hA.z & 0xFFFF0000u);
        acc6 += pA.y * __uint_as_float(hA.w << 16);
        acc7 += pA.y * __uint_as_float(hA.w & 0xFFFF0000u);
        acc0 += pB.y * __uint_as_float(hB.x << 16);
        acc1 += pB.y * __uint_as_float(hB.x & 0xFFFF0000u);
        acc2 += pB.y * __uint_as_float(hB.y << 16);
        acc3 += pB.y * __uint_as_float(hB.y & 0xFFFF0000u);
        acc4 += pB.y * __uint_as_float(hB.z << 16);
        acc5 += pB.y * __uint_as_float(hB.z & 0xFFFF0000u);
        acc6 += pB.y * __uint_as_float(hB.w << 16);
        acc7 += pB.y * __uint_as_float(hB.w & 0xFFFF0000u);
        rs += pA.y + pB.y;
    }
    if (j < b) {                                      // guarded tail, single pass
        int eA = j + q, eB = j + 8 + q;
        float2 pA = (eA < b) ? pairs[eA] : make_float2(__int_as_float(0), 0.f);
        float2 pB = (eB < b) ? pairs[eB] : make_float2(__int_as_float(0), 0.f);
        uint4 hA = *(const uint4*)(h + (((size_t)__float_as_int(pA.x)) << 6) + 8 * fq);
        uint4 hB = *(const uint4*)(h + (((size_t)__float_as_int(pB.x)) << 6) + 8 * fq);
        acc0 += pA.y * __uint_as_float(hA.x << 16);
        acc1 += pA.y * __uint_as_float(hA.x & 0xFFFF0000u);
        acc2 += pA.y * __uint_as_float(hA.y << 16);
        acc3 += pA.y * __uint_as_float(hA.y & 0xFFFF0000u);
        acc4 += pA.y * __uint_as_float(hA.z << 16);
        acc5 += pA.y * __uint_as_float(hA.z & 0xFFFF0000u);
        acc6 += pA.y * __uint_as_float(hA.w << 16);
        acc7 += pA.y * __uint_as_float(hA.w & 0xFFFF0000u);
        acc0 += pB.y * __uint_as_float(hB.x << 16);
        acc1 += pB.y * __uint_as_float(hB.x & 0xFFFF0000u);
        acc2 += pB.y * __uint_as_float(hB.y << 16);
        acc3 += pB.y * __uint_as_float(hB.y & 0xFFFF0000u);
        acc4 += pB.y * __uint_as_float(hB.z << 16);
        acc5 += pB.y * __uint_as_float(hB.z & 0xFFFF0000u);
        acc6 += pB.y * __uint_as_float(hB.w << 16);
        acc7 += pB.y * __uint_as_float(hB.w & 0xFFFF0000u);
        rs += pA.y + pB.y;
    }
#pragma unroll
    for (int off = 8; off <= 32; off <<= 1) {         // reduce across edge slots (q bits)
        acc0 += __shfl_xor(acc0, off, 64);
        acc1 += __shfl_xor(acc1, off, 64);
        acc2 += __shfl_xor(acc2, off, 64);
        acc3 += __shfl_xor(acc3, off, 64);
        acc4 += __shfl_xor(acc4, off, 64);
        acc5 += __shfl_xor(acc5, off, 64);
        acc6 += __shfl_xor(acc6, off, 64);
        acc7 += __shfl_xor(acc7, off, 64);
        rs   += __shfl_xor(rs, off, 64);
    }
    // one result per lane: keep acc[q] = feature 8*fq + q (bit-swap permutation)
    float av = q == 0 ? acc0 : q == 1 ? acc1 : q == 2 ? acc2 : q == 3 ? acc3
             : q == 4 ? acc4 : q == 5 ? acc5 : q == 6 ? acc6 : acc7;
    rs += (rs == 0.f) ? 1.f : 0.f;                    // empty-segment fixup (ee>0 otherwise)
    float ev = av / rs;
    ev = ev > 0.f ? ev : expm1f(ev);
    out0[(size_t)v * FOUT + 8 * fq + q] = ev;         // permuted within 256B row
    if (lane == 0) ersum[v] = rs;                     // fixed rowsum, plain store
}

// ---------- K7: out1 = float(edge) AND out2 /= ersum[e0] (fused, runs LAST) ----------
__global__ __launch_bounds__(256) void k_final(const void* __restrict__ edge, const int* __restrict__ iflag,
                                               const float* __restrict__ ersum,
                                               float* __restrict__ out2, float* __restrict__ out1) {
    int i = blockIdx.x * 256 + threadIdx.x;           // 12500*256 = 2*NE exact
    int i64 = *iflag;
    int v = i64 ? (int)((const long long*)edge)[i] : ((const int*)edge)[i];
    out1[i] = (float)v;
    if (i < NE) {                                     // edge[0..NE) is row 0 = e0
        int e0 = v < 0 ? 0 : (v >= NN ? NN - 1 : v);
        out2[i] = out2[i] / ersum[e0];
    }
}

extern "C" void kernel_launch(void* const* d_in, const int* in_sizes, int n_in,
                              void* d_out, int out_size, void* d_ws, size_t ws_size,
                              hipStream_t stream) {
    // Resolve inputs by element count (all distinct).
    int ix[3] = {0, 1, 2}; int nx = 0;
    int iE = 3, iCol = 4, iRowI = 5, iRes = 6, iW = 8, iA1 = 9, iA2 = 10;
    bool a1seen = false;
    for (int i = 0; i < n_in; i++) {
        int s = in_sizes[i];
        if (s == NN * FIN) { if (nx < 3) ix[nx++] = i; }
        else if (s == 2 * NE) iE = i;
        else if (s == 2 * NN) iCol = i;
        else if (s == NN) iRowI = i;
        else if (s == NE) iRes = i;
        else if (s == FIN * FOUT) iW = i;
        else if (s == 2 * FOUT) { if (!a1seen) { iA1 = i; a1seen = true; } else iA2 = i; }
    }
    const float* input = (const float*)d_in[ix[0]];
    const float* p_h   = (const float*)d_in[ix[1]];
    const float* new_h = (const float*)d_in[ix[2]];
    const void* edge       = d_in[iE];
    const void* edge_col   = d_in[iCol];
    const void* row_i      = d_in[iRowI];
    const void* row_resort = d_in[iRes];
    const float* W  = (const float*)d_in[iW];
    const float* a1 = (const float*)d_in[iA1];
    const float* a2 = (const float*)d_in[iA2];

    // Outputs are FLOAT32, concatenated.
    float* out0 = (float*)d_out;                      // N*FOUT
    float* out1 = out0 + (size_t)NN * FOUT;           // 2*NE
    float* out2 = out1 + (size_t)2 * NE;              // NE (edge_e numerator, then in-place divide)

    // Coarse-scatter scratch: out1 region is free until k_final (last kernel).
    uint2* tmp = (uint2*)out1;

    // ws layout (~29 MB; h region reserved as NN*FOUT floats, used as bf16)
    unsigned short* h = (unsigned short*)d_ws;        // NN*FOUT bf16 (6.4 MB used)
    float2* pairs  = (float2*)((float*)d_ws + (size_t)NN * FOUT); // NE float2 (12.8 MB)
    float*  s1     = (float*)(pairs + NE);
    float*  s2     = s1 + NN;
    float*  s4     = s2 + NN;
    float*  ec     = s4 + NN;                         // reused in place as ex
    float*  scf    = ec + NN;                         // float2[NN]: {s3, ecs}
    float*  mseg   = scf + 2 * (size_t)NN;            // zeroed (atomicMax uint bits)
    float*  ssum   = mseg + NN;                       // zeroed
    int*    bcnt   = (int*)(ssum + NN);               // NB
    int*    start  = bcnt + NB;                       // NN+1 (sentinel)
    int*    bstart = start + NN + 1;                  // NB+1
    int*    cntm   = bstart + NB + 1;                 // NBLK*NB (613 KB)
    int*    colpre = cntm + (size_t)NBLK * NB;        // NBLK*NB (613 KB)
    float*  ersum  = (float*)(colpre + (size_t)NBLK * NB);  // NN
    float*  u      = ersum + NN;                      // 512
    int*    iflag  = (int*)(u + 512);

    hipMemsetAsync(mseg, 0, (size_t)2 * NN * sizeof(float), stream);  // mseg, ssum

    k_su<<<2, 256, 0, stream>>>((const int*)edge, iflag, W, a1, a2, u);
    k_gemm<<<NN / 16, 256, 0, stream>>>(input, W, h);
    k_svec_cnt<<<12500 + NBLK, 256, 0, stream>>>(input, p_h, new_h, u, s1, s2, scf, s4,
                                                 edge, iflag, cntm);
    k_colscore<<<(NN + 255) / 256, 256, 0, stream>>>(s1, s2, edge_col, row_i, iflag, ec, (unsigned int*)mseg);
    k_expsum<<<(NN + 255) / 256, 256, 0, stream>>>(ec, (const unsigned int*)mseg, row_i, iflag, ssum);
    k_norm<<<(NN + 255) / 256, 256, 0, stream>>>(ec, ssum, row_i, iflag, scf);
    k_colscan<<<NB, 1024, 0, stream>>>(cntm, colpre, bcnt);
    k_bscan<<<1, 256, 0, stream>>>(bcnt, bstart, start);
    k_edgeA<<<NBLK, 512, 0, stream>>>((const float2*)scf, s4, edge, row_resort, iflag, bstart, colpre, tmp, out2);
    k_edgeB<<<NB, 512, 0, stream>>>(tmp, bstart, start, pairs);
    k_agg<<<NN / 8, 512, 0, stream>>>(h, pairs, start, ersum, out0);
    k_final<<<2 * NE / 256, 256, 0, stream>>>(edge, iflag, ersum, out2, out1);
}

// Round 11
// 281.730 us; speedup vs baseline: 1.2485x; 1.0331x over previous
//
#include <hip/hip_runtime.h>

#define NN 50000
#define NE 1600000
#define FIN 128
#define FOUT 64
#define ALPHA 0.2f

#define RANGE 256          // destination nodes per bucket
#define NB 196             // ceil(NN / RANGE)
#define EPB 2048           // edges per block in pass A / cnt
#define NBLK 782           // ceil(NE / EPB)

__device__ inline int ldi(const void* p, size_t i, int isi64) {
    int v = isi64 ? (int)((const long long*)p)[i] : ((const int*)p)[i];
    return v < 0 ? 0 : (v >= NN ? NN - 1 : v);  // clamp: no data-dependent OOB
}

// f32 -> bf16 round-to-nearest-even
__device__ inline unsigned short f2bf(float x) {
    unsigned u = __float_as_uint(x);
    return (unsigned short)((u + 0x7FFFu + ((u >> 16) & 1u)) >> 16);
}

// ---------- K0: fused {int-width sniffer | u = W @ {a1l,a1r,a2l,a2r}} ----------
__global__ __launch_bounds__(256) void k_su(const int* __restrict__ edge32, int* __restrict__ iflag,
                                            const float* __restrict__ W, const float* __restrict__ a1,
                                            const float* __restrict__ a2, float* __restrict__ u) {
    if (blockIdx.x == 0) {
        __shared__ int zodd;
        if (threadIdx.x == 0) zodd = 0;
        __syncthreads();
        int z = 0;
        for (int i = threadIdx.x; i < 2048; i += 256)
            if (edge32[2 * i + 1] == 0) z++;    // int64 high words are always 0
        atomicAdd(&zodd, z);
        __syncthreads();
        if (threadIdx.x == 0) *iflag = (zodd > 2000) ? 1 : 0;
    } else {
        int k = threadIdx.x;  // 0..127 active
        if (k < FIN) {
            float u1 = 0.f, u2 = 0.f, u3 = 0.f, u4 = 0.f;
            for (int j = 0; j < FOUT; j++) {
                float w = W[k * FOUT + j];
                u1 += w * a1[j];
                u2 += w * a1[FOUT + j];
                u3 += w * a2[j];
                u4 += w * a2[FOUT + j];
            }
            u[k] = u1; u[128 + k] = u2; u[256 + k] = u3; u[384 + k] = u4;
        }
    }
}

// ---------- K1: h = input @ W  (N x 64, stored bf16 — consumed only by k_agg) ----------
__global__ __launch_bounds__(256) void k_gemm(const float* __restrict__ X,
                                              const float* __restrict__ W,
                                              unsigned short* __restrict__ h) {
    __shared__ float wlds[FIN * FOUT];      // 32 KB
    __shared__ float xlds[4][4][FIN];       // 8 KB
    int tid = threadIdx.x;
    for (int i = tid; i < FIN * FOUT; i += 256) wlds[i] = W[i];
    int wave = tid >> 6, lane = tid & 63;
    int base = blockIdx.x * 16 + wave * 4;  // 3125*16 = 50000 exact
    for (int n0 = 0; n0 < 4; n0++) {
        float2 b = ((const float2*)(X + (size_t)(base + n0) * FIN))[lane];
        xlds[wave][n0][2 * lane] = b.x;
        xlds[wave][n0][2 * lane + 1] = b.y;
    }
    __syncthreads();
    float a0 = 0.f, a1v = 0.f, a2v = 0.f, a3 = 0.f;
    for (int k = 0; k < FIN; k++) {
        float w = wlds[k * FOUT + lane];
        a0  += xlds[wave][0][k] * w;
        a1v += xlds[wave][1][k] * w;
        a2v += xlds[wave][2][k] * w;
        a3  += xlds[wave][3][k] * w;
    }
    h[(size_t)(base + 0) * FOUT + lane] = f2bf(a0);
    h[(size_t)(base + 1) * FOUT + lane] = f2bf(a1v);
    h[(size_t)(base + 2) * FOUT + lane] = f2bf(a2v);
    h[(size_t)(base + 3) * FOUT + lane] = f2bf(a3);
}

// ---------- K1b: fused {per-node score scalars | per-block bucket counts} ----------
__global__ __launch_bounds__(256) void k_svec_cnt(const float* __restrict__ input,
                                                  const float* __restrict__ p_h,
                                                  const float* __restrict__ new_h,
                                                  const float* __restrict__ u,
                                                  float* __restrict__ s1, float* __restrict__ s2,
                                                  float* __restrict__ sc /* float2 as float* */,
                                                  float* __restrict__ s4,
                                                  const void* __restrict__ edge,
                                                  const int* __restrict__ iflag,
                                                  int* __restrict__ cntm) {
    __shared__ int hist[NB];
    int tid = threadIdx.x;
    if (blockIdx.x < 12500) {
        int lane = tid & 63;
        int v = blockIdx.x * 4 + (tid >> 6);
        size_t row = (size_t)v * FIN;
        float2 bi = ((const float2*)(input + row))[lane];
        float2 bp = ((const float2*)(p_h   + row))[lane];
        float2 bn = ((const float2*)(new_h + row))[lane];
        float p1 = bi.x * u[2 * lane]       + bi.y * u[2 * lane + 1];
        float p2 = bp.x * u[128 + 2 * lane] + bp.y * u[128 + 2 * lane + 1];
        float p3 = bn.x * u[256 + 2 * lane] + bn.y * u[256 + 2 * lane + 1];
        float p4 = bi.x * u[384 + 2 * lane] + bi.y * u[384 + 2 * lane + 1];
#pragma unroll
        for (int off = 32; off > 0; off >>= 1) {
            p1 += __shfl_down(p1, off, 64);
            p2 += __shfl_down(p2, off, 64);
            p3 += __shfl_down(p3, off, 64);
            p4 += __shfl_down(p4, off, 64);
        }
        if (lane == 0) { s1[v] = p1; s2[v] = p2; sc[2 * v] = p3; s4[v] = p4; }
    } else {
        int cb = blockIdx.x - 12500;                  // 0..781
        for (int t = tid; t < NB; t += 256) hist[t] = 0;
        __syncthreads();
        int i64 = *iflag;
        int base = cb * EPB;
        int b0[8]; bool act[8];
#pragma unroll
        for (int k = 0; k < 8; k++) {                 // phase 1: 8 independent loads
            int e = base + k * 256 + tid;
            act[k] = e < NE;
            b0[k] = ldi(edge, act[k] ? e : NE - 1, i64) >> 8;
        }
#pragma unroll
        for (int k = 0; k < 8; k++)                   // phase 2: 8 LDS atomics
            if (act[k]) atomicAdd(&hist[b0[k]], 1);
        __syncthreads();
        for (int t = tid; t < NB; t += 256)
            cntm[cb * NB + t] = hist[t];              // plain coalesced row store
    }
}

// ---------- K2: col score + exp + segment max ----------
__global__ void k_colscore(const float* __restrict__ s1, const float* __restrict__ s2,
                           const void* __restrict__ edge_col, const void* __restrict__ row_i,
                           const int* __restrict__ iflag,
                           float* __restrict__ ec, unsigned int* __restrict__ m) {
    int i = blockIdx.x * 256 + threadIdx.x;
    if (i >= NN) return;
    int i64 = *iflag;
    float cs = s1[ldi(edge_col, i, i64)] + s2[i];
    float l = cs > 0.f ? cs : ALPHA * cs;
    float e = expf(-l);                // > 0 always
    ec[i] = e;
    atomicMax(&m[ldi(row_i, i, i64)], __float_as_uint(e));  // init 0, e>0 -> valid
}

// ---------- K3: ex = exp(ec - m) in place; segment sum ----------
__global__ void k_expsum(float* __restrict__ ec, const unsigned int* __restrict__ m,
                         const void* __restrict__ row_i, const int* __restrict__ iflag,
                         float* __restrict__ ssum) {
    int i = blockIdx.x * 256 + threadIdx.x;
    if (i >= NN) return;
    int r = ldi(row_i, i, *iflag);
    float e = expf(ec[i] - __uint_as_float(m[r]));
    ec[i] = e;
    atomicAdd(&ssum[r], e);
}

// ---------- K4: normalize -> sc[i].y = ecs ----------
__global__ void k_norm(const float* __restrict__ ex, const float* __restrict__ ssum,
                       const void* __restrict__ row_i, const int* __restrict__ iflag,
                       float* __restrict__ sc /* float2 as float* */) {
    int i = blockIdx.x * 256 + threadIdx.x;
    if (i >= NN) return;
    sc[2 * i + 1] = ex[i] / (ssum[ldi(row_i, i, *iflag)] + 1e-16f);
}

// ---------- K5b1: per-bucket column scan over 782 blocks -> colpre, bcnt ----------
__global__ __launch_bounds__(1024) void k_colscan(const int* __restrict__ cntm,
                                                  int* __restrict__ colpre,
                                                  int* __restrict__ bcnt) {
    __shared__ int s[1024];
    int b = blockIdx.x, tid = threadIdx.x;
    int x = (tid < NBLK) ? cntm[(size_t)tid * NB + b] : 0;
    s[tid] = x;
    __syncthreads();
    for (int off = 1; off < 1024; off <<= 1) {
        int t = (tid >= off) ? s[tid - off] : 0;
        __syncthreads();
        s[tid] += t;
        __syncthreads();
    }
    if (tid < NBLK) colpre[(size_t)tid * NB + b] = s[tid] - x;  // exclusive within column
    if (tid == 1023) bcnt[b] = s[1023];                         // column total
}

// ---------- K5b2: scan 196 bucket totals -> bstart; sentinels ----------
__global__ __launch_bounds__(256) void k_bscan(const int* __restrict__ bcnt,
                                               int* __restrict__ bstart,
                                               int* __restrict__ start) {
    __shared__ int s[256];
    int tid = threadIdx.x;
    int x = (tid < NB) ? bcnt[tid] : 0;
    s[tid] = x;
    __syncthreads();
    for (int off = 1; off < 256; off <<= 1) {
        int t = (tid >= off) ? s[tid - off] : 0;
        __syncthreads();
        s[tid] += t;
        __syncthreads();
    }
    if (tid < NB) bstart[tid] = s[tid] - x;
    if (tid == 0) { bstart[NB] = NE; start[NN] = NE; }
}

// ---------- K5c pass A: explicit-MLP phase-split; single barrier ----------
// bbase prefetched during hist-zero (independent of hist). Phase 1: 12 index
// loads batched. Phase 2: 8 gathers batched. Phase 3: compute+rank+edge_e.
// Scatter uses bbase+rank directly: NO second/third __syncthreads().
__global__ __launch_bounds__(512) void k_edgeA(const float2* __restrict__ sc, const float* __restrict__ s4,
                                               const void* __restrict__ edge, const void* __restrict__ row_resort,
                                               const int* __restrict__ iflag,
                                               const int* __restrict__ bstart, const int* __restrict__ colpre,
                                               uint2* __restrict__ tmp,
                                               float* __restrict__ edge_e /* = out2 */) {
    __shared__ int hist[NB];
    __shared__ int bbase[NB];
    int tid = threadIdx.x;
    for (int t = tid; t < NB; t += 512) {
        hist[t] = 0;
        bbase[t] = bstart[t] + colpre[(size_t)blockIdx.x * NB + t];  // prefetch, hist-independent
    }
    __syncthreads();
    int i64 = *iflag;
    int base = blockIdx.x * EPB;
    int e0[4], e1[4], rr[4]; bool act[4];
#pragma unroll
    for (int k = 0; k < 4; k++) {                     // phase 1: 12 independent index loads
        int e = base + k * 512 + tid;
        act[k] = e < NE;
        size_t ec = act[k] ? (size_t)e : (size_t)(NE - 1);  // clamped: loads always legal
        e0[k] = ldi(edge, ec, i64);
        e1[k] = ldi(edge, (size_t)NE + ec, i64);
        rr[k] = ldi(row_resort, ec, i64);
    }
    float2 c[4]; float s4v[4];
#pragma unroll
    for (int k = 0; k < 4; k++) {                     // phase 2: 8 independent gathers
        c[k] = sc[rr[k]];
        s4v[k] = s4[e1[k]];
    }
    unsigned key[4]; float val[4]; int rk[4], bk[4];
#pragma unroll
    for (int k = 0; k < 4; k++) {                     // phase 3: compute + rank + numerator
        float rsv = c[k].x + s4v[k];
        float l = rsv > 0.f ? rsv : ALPHA * rsv;
        float ee = expf(-l) * c[k].y;
        if (act[k]) edge_e[base + k * 512 + tid] = ee;
        key[k] = (unsigned)e0[k] | ((unsigned)e1[k] << 16);   // both < 65536
        val[k] = ee;
        bk[k] = e0[k] >> 8;                           // bucket = e0 / RANGE
        rk[k] = act[k] ? atomicAdd(&hist[bk[k]], 1) : 0;      // rank within (block,bucket)
    }
#pragma unroll
    for (int k = 0; k < 4; k++)                       // scatter: no barrier needed
        if (act[k])
            tmp[bbase[bk[k]] + rk[k]] = make_uint2(key[k], __float_as_uint(val[k]));
}

// ---------- K5c pass B: per-node offsets + fine scatter, L2-resident ----------
__global__ __launch_bounds__(512) void k_edgeB(const uint2* __restrict__ tmp,
                                               const int* __restrict__ bstart,
                                               int* __restrict__ start,
                                               float2* __restrict__ pairs) {
    __shared__ int cnt[RANGE];
    __shared__ int s[RANGE];
    __shared__ int cur[RANGE];
    int b = blockIdx.x;
    int tid = threadIdx.x;
    int v0 = b * RANGE;
    if (tid < RANGE) cnt[tid] = 0;
    __syncthreads();
    int lo = bstart[b], hi = bstart[b + 1];
    for (int i = lo + tid; i < hi; i += 512)
        atomicAdd(&cnt[tmp[i].x & 0xFFu], 1);         // e0 & 255 == e0 - v0
    __syncthreads();
    if (tid < RANGE) s[tid] = cnt[tid];
    __syncthreads();
    for (int off = 1; off < RANGE; off <<= 1) {
        int t = 0;
        if (tid < RANGE && tid >= off) t = s[tid - off];
        __syncthreads();
        if (tid < RANGE) s[tid] += t;
        __syncthreads();
    }
    if (tid < RANGE) {
        int g = lo + s[tid] - cnt[tid];               // exclusive prefix + bucket base
        cur[tid] = g;
        int v = v0 + tid;
        if (v < NN) start[v] = g;
    }
    __syncthreads();
    for (int i = lo + tid; i < hi; i += 512) {
        uint2 r = tmp[i];
        int pos = atomicAdd(&cur[r.x & 0xFFu], 1);    // LDS atomic
        pairs[pos] = make_float2(__int_as_float((int)(r.x >> 16)), __uint_as_float(r.y));
    }
}

// ---------- K6: gather-aggregate; 8 edge slots x 8 feats/lane; 1-result/lane epilogue ----------
__global__ __launch_bounds__(512) void k_agg(const unsigned short* __restrict__ h,
                                             const float2* __restrict__ pairs,
                                             const int* __restrict__ start,
                                             float* __restrict__ ersum,
                                             float* __restrict__ out0) {
    int lane = threadIdx.x & 63;
    int q  = lane >> 3;                // edge slot 0..7
    int fq = lane & 7;                 // feature octet: feats 8fq..8fq+7
    int v = blockIdx.x * 8 + (threadIdx.x >> 6);      // 6250*8 = NN exact
    int a = start[v], b = start[v + 1];
    float acc0 = 0.f, acc1 = 0.f, acc2 = 0.f, acc3 = 0.f;
    float acc4 = 0.f, acc5 = 0.f, acc6 = 0.f, acc7 = 0.f, rs = 0.f;
    int bfull = a + ((b - a) & ~15);
    int j = a;
    for (; j < bfull; j += 16) {                      // no bounds checks
        float2 pA = pairs[j + q];
        float2 pB = pairs[j + 8 + q];
        uint4 hA = *(const uint4*)(h + (((size_t)__float_as_int(pA.x)) << 6) + 8 * fq);
        uint4 hB = *(const uint4*)(h + (((size_t)__float_as_int(pB.x)) << 6) + 8 * fq);
        acc0 += pA.y * __uint_as_float(hA.x << 16);
        acc1 += pA.y * __uint_as_float(hA.x & 0xFFFF0000u);
        acc2 += pA.y * __uint_as_float(hA.y << 16);
        acc3 += pA.y * __uint_as_float(hA.y & 0xFFFF0000u);
        acc4 += pA.y * __uint_as_float(hA.z << 16);
        acc5 += pA.y * __uint_as_float(hA.z & 0xFFFF0000u);
        acc6 += pA.y * __uint_as_float(hA.w << 16);
        acc7 += pA.y * __uint_as_float(hA.w & 0xFFFF0000u);
        acc0 += pB.y * __uint_as_float(hB.x << 16);
        acc1 += pB.y * __uint_as_float(hB.x & 0xFFFF0000u);
        acc2 += pB.y * __uint_as_float(hB.y << 16);
        acc3 += pB.y * __uint_as_float(hB.y & 0xFFFF0000u);
        acc4 += pB.y * __uint_as_float(hB.z << 16);
        acc5 += pB.y * __uint_as_float(hB.z & 0xFFFF0000u);
        acc6 += pB.y * __uint_as_float(hB.w << 16);
        acc7 += pB.y * __uint_as_float(hB.w & 0xFFFF0000u);
        rs += pA.y + pB.y;
    }
    if (j < b) {                                      // guarded tail, single pass
        int eA = j + q, eB = j + 8 + q;
        float2 pA = (eA < b) ? pairs[eA] : make_float2(__int_as_float(0), 0.f);
        float2 pB = (eB < b) ? pairs[eB] : make_float2(__int_as_float(0), 0.f);
        uint4 hA = *(const uint4*)(h + (((size_t)__float_as_int(pA.x)) << 6) + 8 * fq);
        uint4 hB = *(const uint4*)(h + (((size_t)__float_as_int(pB.x)) << 6) + 8 * fq);
        acc0 += pA.y * __uint_as_float(hA.x << 16);
        acc1 += pA.y * __uint_as_float(hA.x & 0xFFFF0000u);
        acc2 += pA.y * __uint_as_float(hA.y << 16);
        acc3 += pA.y * __uint_as_float(hA.y & 0xFFFF0000u);
        acc4 += pA.y * __uint_as_float(hA.z << 16);
        acc5 += pA.y * __uint_as_float(hA.z & 0xFFFF0000u);
        acc6 += pA.y * __uint_as_float(hA.w << 16);
        acc7 += pA.y * __uint_as_float(hA.w & 0xFFFF0000u);
        acc0 += pB.y * __uint_as_float(hB.x << 16);
        acc1 += pB.y * __uint_as_float(hB.x & 0xFFFF0000u);
        acc2 += pB.y * __uint_as_float(hB.y << 16);
        acc3 += pB.y * __uint_as_float(hB.y & 0xFFFF0000u);
        acc4 += pB.y * __uint_as_float(hB.z << 16);
        acc5 += pB.y * __uint_as_float(hB.z & 0xFFFF0000u);
        acc6 += pB.y * __uint_as_float(hB.w << 16);
        acc7 += pB.y * __uint_as_float(hB.w & 0xFFFF0000u);
        rs += pA.y + pB.y;
    }
#pragma unroll
    for (int off = 8; off <= 32; off <<= 1) {         // reduce across edge slots (q bits)
        acc0 += __shfl_xor(acc0, off, 64);
        acc1 += __shfl_xor(acc1, off, 64);
        acc2 += __shfl_xor(acc2, off, 64);
        acc3 += __shfl_xor(acc3, off, 64);
        acc4 += __shfl_xor(acc4, off, 64);
        acc5 += __shfl_xor(acc5, off, 64);
        acc6 += __shfl_xor(acc6, off, 64);
        acc7 += __shfl_xor(acc7, off, 64);
        rs   += __shfl_xor(rs, off, 64);
    }
    // one result per lane: keep acc[q] = feature 8*fq + q (bit-swap permutation)
    float av = q == 0 ? acc0 : q == 1 ? acc1 : q == 2 ? acc2 : q == 3 ? acc3
             : q == 4 ? acc4 : q == 5 ? acc5 : q == 6 ? acc6 : acc7;
    rs += (rs == 0.f) ? 1.f : 0.f;                    // empty-segment fixup (ee>0 otherwise)
    float ev = av / rs;
    ev = ev > 0.f ? ev : expm1f(ev);
    out0[(size_t)v * FOUT + 8 * fq + q] = ev;         // permuted within 256B row
    if (lane == 0) ersum[v] = rs;                     // fixed rowsum, plain store
}

// ---------- K7: out1 = float(edge) AND out2 /= ersum[e0] (fused, runs LAST) ----------
__global__ __launch_bounds__(256) void k_final(const void* __restrict__ edge, const int* __restrict__ iflag,
                                               const float* __restrict__ ersum,
                                               float* __restrict__ out2, float* __restrict__ out1) {
    int i = blockIdx.x * 256 + threadIdx.x;           // 12500*256 = 2*NE exact
    int i64 = *iflag;
    int v = i64 ? (int)((const long long*)edge)[i] : ((const int*)edge)[i];
    out1[i] = (float)v;
    if (i < NE) {                                     // edge[0..NE) is row 0 = e0
        int e0 = v < 0 ? 0 : (v >= NN ? NN - 1 : v);
        out2[i] = out2[i] / ersum[e0];
    }
}

extern "C" void kernel_launch(void* const* d_in, const int* in_sizes, int n_in,
                              void* d_out, int out_size, void* d_ws, size_t ws_size,
                              hipStream_t stream) {
    // Resolve inputs by element count (all distinct).
    int ix[3] = {0, 1, 2}; int nx = 0;
    int iE = 3, iCol = 4, iRowI = 5, iRes = 6, iW = 8, iA1 = 9, iA2 = 10;
    bool a1seen = false;
    for (int i = 0; i < n_in; i++) {
        int s = in_sizes[i];
        if (s == NN * FIN) { if (nx < 3) ix[nx++] = i; }
        else if (s == 2 * NE) iE = i;
        else if (s == 2 * NN) iCol = i;
        else if (s == NN) iRowI = i;
        else if (s == NE) iRes = i;
        else if (s == FIN * FOUT) iW = i;
        else if (s == 2 * FOUT) { if (!a1seen) { iA1 = i; a1seen = true; } else iA2 = i; }
    }
    const float* input = (const float*)d_in[ix[0]];
    const float* p_h   = (const float*)d_in[ix[1]];
    const float* new_h = (const float*)d_in[ix[2]];
    const void* edge       = d_in[iE];
    const void* edge_col   = d_in[iCol];
    const void* row_i      = d_in[iRowI];
    const void* row_resort = d_in[iRes];
    const float* W  = (const float*)d_in[iW];
    const float* a1 = (const float*)d_in[iA1];
    const float* a2 = (const float*)d_in[iA2];

    // Outputs are FLOAT32, concatenated.
    float* out0 = (float*)d_out;                      // N*FOUT
    float* out1 = out0 + (size_t)NN * FOUT;           // 2*NE
    float* out2 = out1 + (size_t)2 * NE;              // NE (edge_e numerator, then in-place divide)

    // Coarse-scatter scratch: out1 region is free until k_final (last kernel).
    uint2* tmp = (uint2*)out1;

    // ws layout (~29 MB; h region reserved as NN*FOUT floats, used as bf16)
    unsigned short* h = (unsigned short*)d_ws;        // NN*FOUT bf16 (6.4 MB used)
    float2* pairs  = (float2*)((float*)d_ws + (size_t)NN * FOUT); // NE float2 (12.8 MB)
    float*  s1     = (float*)(pairs + NE);
    float*  s2     = s1 + NN;
    float*  s4     = s2 + NN;
    float*  ec     = s4 + NN;                         // reused in place as ex
    float*  scf    = ec + NN;                         // float2[NN]: {s3, ecs}
    float*  mseg   = scf + 2 * (size_t)NN;            // zeroed (atomicMax uint bits)
    float*  ssum   = mseg + NN;                       // zeroed
    int*    bcnt   = (int*)(ssum + NN);               // NB
    int*    start  = bcnt + NB;                       // NN+1 (sentinel)
    int*    bstart = start + NN + 1;                  // NB+1
    int*    cntm   = bstart + NB + 1;                 // NBLK*NB (613 KB)
    int*    colpre = cntm + (size_t)NBLK * NB;        // NBLK*NB (613 KB)
    float*  ersum  = (float*)(colpre + (size_t)NBLK * NB);  // NN
    float*  u      = ersum + NN;                      // 512
    int*    iflag  = (int*)(u + 512);

    hipMemsetAsync(mseg, 0, (size_t)2 * NN * sizeof(float), stream);  // mseg, ssum

    k_su<<<2, 256, 0, stream>>>((const int*)edge, iflag, W, a1, a2, u);
    k_gemm<<<NN / 16, 256, 0, stream>>>(input, W, h);
    k_svec_cnt<<<12500 + NBLK, 256, 0, stream>>>(input, p_h, new_h, u, s1, s2, scf, s4,
                                                 edge, iflag, cntm);
    k_colscore<<<(NN + 255) / 256, 256, 0, stream>>>(s1, s2, edge_col, row_i, iflag, ec, (unsigned int*)mseg);
    k_expsum<<<(NN + 255) / 256, 256, 0, stream>>>(ec, (const unsigned int*)mseg, row_i, iflag, ssum);
    k_norm<<<(NN + 255) / 256, 256, 0, stream>>>(ec, ssum, row_i, iflag, scf);
    k_colscan<<<NB, 1024, 0, stream>>>(cntm, colpre, bcnt);
    k_bscan<<<1, 256, 0, stream>>>(bcnt, bstart, start);
    k_edgeA<<<NBLK, 512, 0, stream>>>((const float2*)scf, s4, edge, row_resort, iflag, bstart, colpre, tmp, out2);
    k_edgeB<<<NB, 512, 0, stream>>>(tmp, bstart, start, pairs);
    k_agg<<<NN / 8, 512, 0, stream>>>(h, pairs, start, ersum, out0);
    k_final<<<2 * NE / 256, 256, 0, stream>>>(edge, iflag, ersum, out2, out1);
}

// Round 12
// 280.529 us; speedup vs baseline: 1.2539x; 1.0043x over previous
//
#include <hip/hip_runtime.h>

#define NN 50000
#define NE 1600000
#define FIN 128
#define FOUT 64
#define ALPHA 0.2f

#define RANGE 256          // destination nodes per bucket
#define NB 196             // ceil(NN / RANGE)
#define EPB 2048           // edges per block in pass A / cnt
#define NBLK 782           // ceil(NE / EPB)

typedef float v2f __attribute__((ext_vector_type(2)));

__device__ inline int ldi(const void* p, size_t i, int isi64) {
    int v = isi64 ? (int)((const long long*)p)[i] : ((const int*)p)[i];
    return v < 0 ? 0 : (v >= NN ? NN - 1 : v);  // clamp: no data-dependent OOB
}

// f32 -> bf16 round-to-nearest-even
__device__ inline unsigned short f2bf(float x) {
    unsigned u = __float_as_uint(x);
    return (unsigned short)((u + 0x7FFFu + ((u >> 16) & 1u)) >> 16);
}

// unpack uint (2 bf16) -> v2f {even, odd}
__device__ inline v2f bfu2(unsigned u) {
    v2f r;
    r.x = __uint_as_float(u << 16);
    r.y = __uint_as_float(u & 0xFFFF0000u);
    return r;
}

// ---------- K0: fused {int-width sniffer | u = W @ {a1l,a1r,a2l,a2r}} ----------
__global__ __launch_bounds__(256) void k_su(const int* __restrict__ edge32, int* __restrict__ iflag,
                                            const float* __restrict__ W, const float* __restrict__ a1,
                                            const float* __restrict__ a2, float* __restrict__ u) {
    if (blockIdx.x == 0) {
        __shared__ int zodd;
        if (threadIdx.x == 0) zodd = 0;
        __syncthreads();
        int z = 0;
        for (int i = threadIdx.x; i < 2048; i += 256)
            if (edge32[2 * i + 1] == 0) z++;    // int64 high words are always 0
        atomicAdd(&zodd, z);
        __syncthreads();
        if (threadIdx.x == 0) *iflag = (zodd > 2000) ? 1 : 0;
    } else {
        int k = threadIdx.x;  // 0..127 active
        if (k < FIN) {
            float u1 = 0.f, u2 = 0.f, u3 = 0.f, u4 = 0.f;
            for (int j = 0; j < FOUT; j++) {
                float w = W[k * FOUT + j];
                u1 += w * a1[j];
                u2 += w * a1[FOUT + j];
                u3 += w * a2[j];
                u4 += w * a2[FOUT + j];
            }
            u[k] = u1; u[128 + k] = u2; u[256 + k] = u3; u[384 + k] = u4;
        }
    }
}

// ---------- K1: h = input @ W  (N x 64, stored bf16 — consumed only by k_agg) ----------
__global__ __launch_bounds__(256) void k_gemm(const float* __restrict__ X,
                                              const float* __restrict__ W,
                                              unsigned short* __restrict__ h) {
    __shared__ float wlds[FIN * FOUT];      // 32 KB
    __shared__ float xlds[4][4][FIN];       // 8 KB
    int tid = threadIdx.x;
    for (int i = tid; i < FIN * FOUT; i += 256) wlds[i] = W[i];
    int wave = tid >> 6, lane = tid & 63;
    int base = blockIdx.x * 16 + wave * 4;  // 3125*16 = 50000 exact
    for (int n0 = 0; n0 < 4; n0++) {
        float2 b = ((const float2*)(X + (size_t)(base + n0) * FIN))[lane];
        xlds[wave][n0][2 * lane] = b.x;
        xlds[wave][n0][2 * lane + 1] = b.y;
    }
    __syncthreads();
    float a0 = 0.f, a1v = 0.f, a2v = 0.f, a3 = 0.f;
    for (int k = 0; k < FIN; k++) {
        float w = wlds[k * FOUT + lane];
        a0  += xlds[wave][0][k] * w;
        a1v += xlds[wave][1][k] * w;
        a2v += xlds[wave][2][k] * w;
        a3  += xlds[wave][3][k] * w;
    }
    h[(size_t)(base + 0) * FOUT + lane] = f2bf(a0);
    h[(size_t)(base + 1) * FOUT + lane] = f2bf(a1v);
    h[(size_t)(base + 2) * FOUT + lane] = f2bf(a2v);
    h[(size_t)(base + 3) * FOUT + lane] = f2bf(a3);
}

// ---------- K1b: fused {per-node score scalars | per-block bucket counts} ----------
__global__ __launch_bounds__(256) void k_svec_cnt(const float* __restrict__ input,
                                                  const float* __restrict__ p_h,
                                                  const float* __restrict__ new_h,
                                                  const float* __restrict__ u,
                                                  float* __restrict__ s1, float* __restrict__ s2,
                                                  float* __restrict__ sc /* float2 as float* */,
                                                  float* __restrict__ s4,
                                                  const void* __restrict__ edge,
                                                  const int* __restrict__ iflag,
                                                  int* __restrict__ cntm) {
    __shared__ int hist[NB];
    int tid = threadIdx.x;
    if (blockIdx.x < 12500) {
        int lane = tid & 63;
        int v = blockIdx.x * 4 + (tid >> 6);
        size_t row = (size_t)v * FIN;
        float2 bi = ((const float2*)(input + row))[lane];
        float2 bp = ((const float2*)(p_h   + row))[lane];
        float2 bn = ((const float2*)(new_h + row))[lane];
        float p1 = bi.x * u[2 * lane]       + bi.y * u[2 * lane + 1];
        float p2 = bp.x * u[128 + 2 * lane] + bp.y * u[128 + 2 * lane + 1];
        float p3 = bn.x * u[256 + 2 * lane] + bn.y * u[256 + 2 * lane + 1];
        float p4 = bi.x * u[384 + 2 * lane] + bi.y * u[384 + 2 * lane + 1];
#pragma unroll
        for (int off = 32; off > 0; off >>= 1) {
            p1 += __shfl_down(p1, off, 64);
            p2 += __shfl_down(p2, off, 64);
            p3 += __shfl_down(p3, off, 64);
            p4 += __shfl_down(p4, off, 64);
        }
        if (lane == 0) { s1[v] = p1; s2[v] = p2; sc[2 * v] = p3; s4[v] = p4; }
    } else {
        int cb = blockIdx.x - 12500;                  // 0..781
        for (int t = tid; t < NB; t += 256) hist[t] = 0;
        __syncthreads();
        int i64 = *iflag;
        int base = cb * EPB;
        int b0[8]; bool act[8];
#pragma unroll
        for (int k = 0; k < 8; k++) {                 // phase 1: 8 independent loads
            int e = base + k * 256 + tid;
            act[k] = e < NE;
            b0[k] = ldi(edge, act[k] ? e : NE - 1, i64) >> 8;
        }
#pragma unroll
        for (int k = 0; k < 8; k++)                   // phase 2: 8 LDS atomics
            if (act[k]) atomicAdd(&hist[b0[k]], 1);
        __syncthreads();
        for (int t = tid; t < NB; t += 256)
            cntm[cb * NB + t] = hist[t];              // plain coalesced row store
    }
}

// ---------- K2: col score + exp + segment max ----------
__global__ void k_colscore(const float* __restrict__ s1, const float* __restrict__ s2,
                           const void* __restrict__ edge_col, const void* __restrict__ row_i,
                           const int* __restrict__ iflag,
                           float* __restrict__ ec, unsigned int* __restrict__ m) {
    int i = blockIdx.x * 256 + threadIdx.x;
    if (i >= NN) return;
    int i64 = *iflag;
    float cs = s1[ldi(edge_col, i, i64)] + s2[i];
    float l = cs > 0.f ? cs : ALPHA * cs;
    float e = expf(-l);                // > 0 always
    ec[i] = e;
    atomicMax(&m[ldi(row_i, i, i64)], __float_as_uint(e));  // init 0, e>0 -> valid
}

// ---------- K3: ex = exp(ec - m) in place; segment sum ----------
__global__ void k_expsum(float* __restrict__ ec, const unsigned int* __restrict__ m,
                         const void* __restrict__ row_i, const int* __restrict__ iflag,
                         float* __restrict__ ssum) {
    int i = blockIdx.x * 256 + threadIdx.x;
    if (i >= NN) return;
    int r = ldi(row_i, i, *iflag);
    float e = expf(ec[i] - __uint_as_float(m[r]));
    ec[i] = e;
    atomicAdd(&ssum[r], e);
}

// ---------- K4: normalize -> sc[i].y = ecs ----------
__global__ void k_norm(const float* __restrict__ ex, const float* __restrict__ ssum,
                       const void* __restrict__ row_i, const int* __restrict__ iflag,
                       float* __restrict__ sc /* float2 as float* */) {
    int i = blockIdx.x * 256 + threadIdx.x;
    if (i >= NN) return;
    sc[2 * i + 1] = ex[i] / (ssum[ldi(row_i, i, *iflag)] + 1e-16f);
}

// ---------- K5b1: per-bucket column scan over 782 blocks -> colpre, bcnt ----------
__global__ __launch_bounds__(1024) void k_colscan(const int* __restrict__ cntm,
                                                  int* __restrict__ colpre,
                                                  int* __restrict__ bcnt) {
    __shared__ int s[1024];
    int b = blockIdx.x, tid = threadIdx.x;
    int x = (tid < NBLK) ? cntm[(size_t)tid * NB + b] : 0;
    s[tid] = x;
    __syncthreads();
    for (int off = 1; off < 1024; off <<= 1) {
        int t = (tid >= off) ? s[tid - off] : 0;
        __syncthreads();
        s[tid] += t;
        __syncthreads();
    }
    if (tid < NBLK) colpre[(size_t)tid * NB + b] = s[tid] - x;  // exclusive within column
    if (tid == 1023) bcnt[b] = s[1023];                         // column total
}

// ---------- K5b2: scan 196 bucket totals -> bstart; sentinels ----------
__global__ __launch_bounds__(256) void k_bscan(const int* __restrict__ bcnt,
                                               int* __restrict__ bstart,
                                               int* __restrict__ start) {
    __shared__ int s[256];
    int tid = threadIdx.x;
    int x = (tid < NB) ? bcnt[tid] : 0;
    s[tid] = x;
    __syncthreads();
    for (int off = 1; off < 256; off <<= 1) {
        int t = (tid >= off) ? s[tid - off] : 0;
        __syncthreads();
        s[tid] += t;
        __syncthreads();
    }
    if (tid < NB) bstart[tid] = s[tid] - x;
    if (tid == 0) { bstart[NB] = NE; start[NN] = NE; }
}

// ---------- K5c pass A: explicit-MLP phase-split; single barrier ----------
__global__ __launch_bounds__(512) void k_edgeA(const float2* __restrict__ sc, const float* __restrict__ s4,
                                               const void* __restrict__ edge, const void* __restrict__ row_resort,
                                               const int* __restrict__ iflag,
                                               const int* __restrict__ bstart, const int* __restrict__ colpre,
                                               uint2* __restrict__ tmp,
                                               float* __restrict__ edge_e /* = out2 */) {
    __shared__ int hist[NB];
    __shared__ int bbase[NB];
    int tid = threadIdx.x;
    for (int t = tid; t < NB; t += 512) {
        hist[t] = 0;
        bbase[t] = bstart[t] + colpre[(size_t)blockIdx.x * NB + t];  // prefetch, hist-independent
    }
    __syncthreads();
    int i64 = *iflag;
    int base = blockIdx.x * EPB;
    int e0[4], e1[4], rr[4]; bool act[4];
#pragma unroll
    for (int k = 0; k < 4; k++) {                     // phase 1: 12 independent index loads
        int e = base + k * 512 + tid;
        act[k] = e < NE;
        size_t ec = act[k] ? (size_t)e : (size_t)(NE - 1);  // clamped: loads always legal
        e0[k] = ldi(edge, ec, i64);
        e1[k] = ldi(edge, (size_t)NE + ec, i64);
        rr[k] = ldi(row_resort, ec, i64);
    }
    float2 c[4]; float s4v[4];
#pragma unroll
    for (int k = 0; k < 4; k++) {                     // phase 2: 8 independent gathers
        c[k] = sc[rr[k]];
        s4v[k] = s4[e1[k]];
    }
    unsigned key[4]; float val[4]; int rk[4], bk[4];
#pragma unroll
    for (int k = 0; k < 4; k++) {                     // phase 3: compute + rank + numerator
        float rsv = c[k].x + s4v[k];
        float l = rsv > 0.f ? rsv : ALPHA * rsv;
        float ee = expf(-l) * c[k].y;
        if (act[k]) edge_e[base + k * 512 + tid] = ee;
        key[k] = (unsigned)e0[k] | ((unsigned)e1[k] << 16);   // both < 65536
        val[k] = ee;
        bk[k] = e0[k] >> 8;                           // bucket = e0 / RANGE
        rk[k] = act[k] ? atomicAdd(&hist[bk[k]], 1) : 0;      // rank within (block,bucket)
    }
#pragma unroll
    for (int k = 0; k < 4; k++)                       // scatter: no barrier needed
        if (act[k])
            tmp[bbase[bk[k]] + rk[k]] = make_uint2(key[k], __float_as_uint(val[k]));
}

// ---------- K5c pass B: per-node offsets + fine scatter, L2-resident ----------
__global__ __launch_bounds__(512) void k_edgeB(const uint2* __restrict__ tmp,
                                               const int* __restrict__ bstart,
                                               int* __restrict__ start,
                                               float2* __restrict__ pairs) {
    __shared__ int cnt[RANGE];
    __shared__ int s[RANGE];
    __shared__ int cur[RANGE];
    int b = blockIdx.x;
    int tid = threadIdx.x;
    int v0 = b * RANGE;
    if (tid < RANGE) cnt[tid] = 0;
    __syncthreads();
    int lo = bstart[b], hi = bstart[b + 1];
    for (int i = lo + tid; i < hi; i += 512)
        atomicAdd(&cnt[tmp[i].x & 0xFFu], 1);         // e0 & 255 == e0 - v0
    __syncthreads();
    if (tid < RANGE) s[tid] = cnt[tid];
    __syncthreads();
    for (int off = 1; off < RANGE; off <<= 1) {
        int t = 0;
        if (tid < RANGE && tid >= off) t = s[tid - off];
        __syncthreads();
        if (tid < RANGE) s[tid] += t;
        __syncthreads();
    }
    if (tid < RANGE) {
        int g = lo + s[tid] - cnt[tid];               // exclusive prefix + bucket base
        cur[tid] = g;
        int v = v0 + tid;
        if (v < NN) start[v] = g;
    }
    __syncthreads();
    for (int i = lo + tid; i < hi; i += 512) {
        uint2 r = tmp[i];
        int pos = atomicAdd(&cur[r.x & 0xFFu], 1);    // LDS atomic
        pairs[pos] = make_float2(__int_as_float((int)(r.x >> 16)), __uint_as_float(r.y));
    }
}

// ---------- K6: gather-aggregate; packed-f32 accumulators (v_pk_fma_f32) ----------
// 8 edge slots x 8 feats/lane as before, but the 8 scalar accumulators become
// 4 v2f accumulators -> LLVM forms v_pk_fma_f32: 16 packed FMA per 16-edge
// iteration instead of 32 scalar, and the epilogue butterfly adds are packed.
__global__ __launch_bounds__(512) void k_agg(const unsigned short* __restrict__ h,
                                             const float2* __restrict__ pairs,
                                             const int* __restrict__ start,
                                             float* __restrict__ ersum,
                                             float* __restrict__ out0) {
    int lane = threadIdx.x & 63;
    int q  = lane >> 3;                // edge slot 0..7
    int fq = lane & 7;                 // feature octet: feats 8fq..8fq+7
    int v = blockIdx.x * 8 + (threadIdx.x >> 6);      // 6250*8 = NN exact
    int a = start[v], b = start[v + 1];
    v2f a01 = {0.f, 0.f}, a23 = {0.f, 0.f}, a45 = {0.f, 0.f}, a67 = {0.f, 0.f};
    float rs = 0.f;
    int bfull = a + ((b - a) & ~15);
    int j = a;
    for (; j < bfull; j += 16) {                      // no bounds checks
        float2 pA = pairs[j + q];
        float2 pB = pairs[j + 8 + q];
        uint4 hA = *(const uint4*)(h + (((size_t)__float_as_int(pA.x)) << 6) + 8 * fq);
        uint4 hB = *(const uint4*)(h + (((size_t)__float_as_int(pB.x)) << 6) + 8 * fq);
        v2f eA = {pA.y, pA.y}, eB = {pB.y, pB.y};
        a01 += eA * bfu2(hA.x);
        a23 += eA * bfu2(hA.y);
        a45 += eA * bfu2(hA.z);
        a67 += eA * bfu2(hA.w);
        a01 += eB * bfu2(hB.x);
        a23 += eB * bfu2(hB.y);
        a45 += eB * bfu2(hB.z);
        a67 += eB * bfu2(hB.w);
        rs += pA.y + pB.y;
    }
    if (j < b) {                                      // guarded tail, single pass
        int eAi = j + q, eBi = j + 8 + q;
        float2 pA = (eAi < b) ? pairs[eAi] : make_float2(__int_as_float(0), 0.f);
        float2 pB = (eBi < b) ? pairs[eBi] : make_float2(__int_as_float(0), 0.f);
        uint4 hA = *(const uint4*)(h + (((size_t)__float_as_int(pA.x)) << 6) + 8 * fq);
        uint4 hB = *(const uint4*)(h + (((size_t)__float_as_int(pB.x)) << 6) + 8 * fq);
        v2f eA = {pA.y, pA.y}, eB = {pB.y, pB.y};
        a01 += eA * bfu2(hA.x);
        a23 += eA * bfu2(hA.y);
        a45 += eA * bfu2(hA.z);
        a67 += eA * bfu2(hA.w);
        a01 += eB * bfu2(hB.x);
        a23 += eB * bfu2(hB.y);
        a45 += eB * bfu2(hB.z);
        a67 += eB * bfu2(hB.w);
        rs += pA.y + pB.y;
    }
#pragma unroll
    for (int off = 8; off <= 32; off <<= 1) {         // reduce across edge slots (q bits)
        v2f t01, t23, t45, t67;
        t01.x = __shfl_xor(a01.x, off, 64); t01.y = __shfl_xor(a01.y, off, 64);
        t23.x = __shfl_xor(a23.x, off, 64); t23.y = __shfl_xor(a23.y, off, 64);
        t45.x = __shfl_xor(a45.x, off, 64); t45.y = __shfl_xor(a45.y, off, 64);
        t67.x = __shfl_xor(a67.x, off, 64); t67.y = __shfl_xor(a67.y, off, 64);
        a01 += t01; a23 += t23; a45 += t45; a67 += t67;
        rs  += __shfl_xor(rs, off, 64);
    }
    // one result per lane: keep feature 8*fq + q (pair q>>1, component q&1)
    v2f ap = (q >> 1) == 0 ? a01 : (q >> 1) == 1 ? a23 : (q >> 1) == 2 ? a45 : a67;
    float av = (q & 1) ? ap.y : ap.x;
    rs += (rs == 0.f) ? 1.f : 0.f;                    // empty-segment fixup (ee>0 otherwise)
    float ev = av / rs;
    ev = ev > 0.f ? ev : expm1f(ev);
    out0[(size_t)v * FOUT + 8 * fq + q] = ev;         // permuted within 256B row
    if (lane == 0) ersum[v] = rs;                     // fixed rowsum, plain store
}

// ---------- K7: out1 = float(edge) AND out2 /= ersum[e0] (fused, runs LAST) ----------
__global__ __launch_bounds__(256) void k_final(const void* __restrict__ edge, const int* __restrict__ iflag,
                                               const float* __restrict__ ersum,
                                               float* __restrict__ out2, float* __restrict__ out1) {
    int i = blockIdx.x * 256 + threadIdx.x;           // 12500*256 = 2*NE exact
    int i64 = *iflag;
    int v = i64 ? (int)((const long long*)edge)[i] : ((const int*)edge)[i];
    out1[i] = (float)v;
    if (i < NE) {                                     // edge[0..NE) is row 0 = e0
        int e0 = v < 0 ? 0 : (v >= NN ? NN - 1 : v);
        out2[i] = out2[i] / ersum[e0];
    }
}

extern "C" void kernel_launch(void* const* d_in, const int* in_sizes, int n_in,
                              void* d_out, int out_size, void* d_ws, size_t ws_size,
                              hipStream_t stream) {
    // Resolve inputs by element count (all distinct).
    int ix[3] = {0, 1, 2}; int nx = 0;
    int iE = 3, iCol = 4, iRowI = 5, iRes = 6, iW = 8, iA1 = 9, iA2 = 10;
    bool a1seen = false;
    for (int i = 0; i < n_in; i++) {
        int s = in_sizes[i];
        if (s == NN * FIN) { if (nx < 3) ix[nx++] = i; }
        else if (s == 2 * NE) iE = i;
        else if (s == 2 * NN) iCol = i;
        else if (s == NN) iRowI = i;
        else if (s == NE) iRes = i;
        else if (s == FIN * FOUT) iW = i;
        else if (s == 2 * FOUT) { if (!a1seen) { iA1 = i; a1seen = true; } else iA2 = i; }
    }
    const float* input = (const float*)d_in[ix[0]];
    const float* p_h   = (const float*)d_in[ix[1]];
    const float* new_h = (const float*)d_in[ix[2]];
    const void* edge       = d_in[iE];
    const void* edge_col   = d_in[iCol];
    const void* row_i      = d_in[iRowI];
    const void* row_resort = d_in[iRes];
    const float* W  = (const float*)d_in[iW];
    const float* a1 = (const float*)d_in[iA1];
    const float* a2 = (const float*)d_in[iA2];

    // Outputs are FLOAT32, concatenated.
    float* out0 = (float*)d_out;                      // N*FOUT
    float* out1 = out0 + (size_t)NN * FOUT;           // 2*NE
    float* out2 = out1 + (size_t)2 * NE;              // NE (edge_e numerator, then in-place divide)

    // Coarse-scatter scratch: out1 region is free until k_final (last kernel).
    uint2* tmp = (uint2*)out1;

    // ws layout (~29 MB; h region reserved as NN*FOUT floats, used as bf16)
    unsigned short* h = (unsigned short*)d_ws;        // NN*FOUT bf16 (6.4 MB used)
    float2* pairs  = (float2*)((float*)d_ws + (size_t)NN * FOUT); // NE float2 (12.8 MB)
    float*  s1     = (float*)(pairs + NE);
    float*  s2     = s1 + NN;
    float*  s4     = s2 + NN;
    float*  ec     = s4 + NN;                         // reused in place as ex
    float*  scf    = ec + NN;                         // float2[NN]: {s3, ecs}
    float*  mseg   = scf + 2 * (size_t)NN;            // zeroed (atomicMax uint bits)
    float*  ssum   = mseg + NN;                       // zeroed
    int*    bcnt   = (int*)(ssum + NN);               // NB
    int*    start  = bcnt + NB;                       // NN+1 (sentinel)
    int*    bstart = start + NN + 1;                  // NB+1
    int*    cntm   = bstart + NB + 1;                 // NBLK*NB (613 KB)
    int*    colpre = cntm + (size_t)NBLK * NB;        // NBLK*NB (613 KB)
    float*  ersum  = (float*)(colpre + (size_t)NBLK * NB);  // NN
    float*  u      = ersum + NN;                      // 512
    int*    iflag  = (int*)(u + 512);

    hipMemsetAsync(mseg, 0, (size_t)2 * NN * sizeof(float), stream);  // mseg, ssum

    k_su<<<2, 256, 0, stream>>>((const int*)edge, iflag, W, a1, a2, u);
    k_gemm<<<NN / 16, 256, 0, stream>>>(input, W, h);
    k_svec_cnt<<<12500 + NBLK, 256, 0, stream>>>(input, p_h, new_h, u, s1, s2, scf, s4,
                                                 edge, iflag, cntm);
    k_colscore<<<(NN + 255) / 256, 256, 0, stream>>>(s1, s2, edge_col, row_i, iflag, ec, (unsigned int*)mseg);
    k_expsum<<<(NN + 255) / 256, 256, 0, stream>>>(ec, (const unsigned int*)mseg, row_i, iflag, ssum);
    k_norm<<<(NN + 255) / 256, 256, 0, stream>>>(ec, ssum, row_i, iflag, scf);
    k_colscan<<<NB, 1024, 0, stream>>>(cntm, colpre, bcnt);
    k_bscan<<<1, 256, 0, stream>>>(bcnt, bstart, start);
    k_edgeA<<<NBLK, 512, 0, stream>>>((const float2*)scf, s4, edge, row_resort, iflag, bstart, colpre, tmp, out2);
    k_edgeB<<<NB, 512, 0, stream>>>(tmp, bstart, start, pairs);
    k_agg<<<NN / 8, 512, 0, stream>>>(h, pairs, start, ersum, out0);
    k_final<<<2 * NE / 256, 256, 0, stream>>>(edge, iflag, ersum, out2, out1);
}